// Round 9
// baseline (707.884 us; speedup 1.0000x reference)
//
#include <hip/hip_runtime.h>

typedef unsigned short u16;
typedef unsigned int u32;
typedef __attribute__((ext_vector_type(8))) short bf16x8;
typedef __attribute__((ext_vector_type(4))) float f32x4;
typedef __attribute__((ext_vector_type(16))) float f32x16;

#define NH 32
#define NKV 8
#define HD 128
#define SEQ 2048
#define DMODEL 4096
#define QKVN 6144
#define RMS_EPS 1e-6f
#define SM_SCALE 0.08838834764831845f
#define NEG_INF -1e30f

#define AS1 __attribute__((address_space(1)))
#define AS3 __attribute__((address_space(3)))

__device__ __forceinline__ u16 f2bf(float f) {
  unsigned int u = __float_as_uint(f);
  u += 0x7FFFu + ((u >> 16) & 1u);
  return (u16)(u >> 16);
}
__device__ __forceinline__ float bf2f(u16 b) {
  return __uint_as_float(((unsigned int)b) << 16);
}
__device__ __forceinline__ u32 packbf(float lo, float hi) {
  u32 a = __float_as_uint(lo) + 0x8000u;
  u32 b = __float_as_uint(hi) + 0x8000u;
  return __builtin_amdgcn_perm(b, a, 0x07060302u);
}

__device__ __forceinline__ f32x4 mfma16(bf16x8 a, bf16x8 b, f32x4 c) {
  return __builtin_amdgcn_mfma_f32_16x16x32_bf16(a, b, c, 0, 0, 0);
}
__device__ __forceinline__ f32x16 mfma32(bf16x8 a, bf16x8 b, f32x16 c) {
  return __builtin_amdgcn_mfma_f32_32x32x16_bf16(a, b, c, 0, 0, 0);
}

__device__ __forceinline__ void stage16(const u16* g, u16* l) {
  __builtin_amdgcn_global_load_lds((const AS1 u32*)g, (AS3 u32*)l, 16, 0, 0);
}

// ---------------- convert x: f32 -> bf16 ----------------
__global__ __launch_bounds__(256) void cvt_f32_bf16(const float* __restrict__ in,
                                                    u16* __restrict__ out, int n4) {
  int stride = gridDim.x * blockDim.x;
  for (int i = blockIdx.x * blockDim.x + threadIdx.x; i < n4; i += stride) {
    float4 v = ((const float4*)in)[i];
    ushort4 o;
    o.x = f2bf(v.x); o.y = f2bf(v.y); o.z = f2bf(v.z); o.w = f2bf(v.w);
    ((ushort4*)out)[i] = o;
  }
}

// ---------------- transpose-convert W[K=4096][N] f32 -> Wt[rowoff+N][4096] bf16 ----------------
__global__ __launch_bounds__(256) void tconv(const float* __restrict__ W, u16* __restrict__ Wt,
                                             int N, int rowoff) {
  __shared__ float t[32][33];
  int n0 = blockIdx.x * 32, k0 = blockIdx.y * 32;
  int tx = threadIdx.x, ty = threadIdx.y;  // (32,8)
#pragma unroll
  for (int i = 0; i < 4; ++i)
    t[ty + i * 8][tx] = W[(size_t)(k0 + ty + i * 8) * N + n0 + tx];
  __syncthreads();
#pragma unroll
  for (int i = 0; i < 4; ++i)
    Wt[(size_t)(rowoff + n0 + ty + i * 8) * DMODEL + k0 + tx] = f2bf(t[tx][ty + i * 8]);
}

__device__ __forceinline__ void storeC(u16* p, float v) { *p = f2bf(v); }
__device__ __forceinline__ void storeC(float* p, float v) { *p = v; }

// ---------------- GEMM 256x256, BK=32, 4-deep counted-vmcnt pipeline (T2+T4+T5+T1) ----
// 8 waves (2M x 4N), per-wave 128x64 output (8x4 16x16 frags), 32 MFMA / K-step.
// LDS: As[4][256x32], Bs[4][256x32] = 128KB; tile j -> buf j&3.
// Pipeline: prologue stages tiles 0..2; iter j: stage(j+3) -> vmcnt(12) (drains tile j,
// 3 tiles stay in flight) -> s_barrier -> compute(j) -> s_barrier. Tail: vmcnt 8/4/0.
// Swizzle (T2): LDS slot ^= (row ^ (row>>2)) & 3 (16B slots, 64B rows) -> reads are
// 2-way max. Applied as pre-swizzled gload source + swizzled read offsets (involution).
template <typename OutT>
__global__ __launch_bounds__(512, 2) void gemm256(const u16* __restrict__ A, const u16* __restrict__ Bt,
                                                  OutT* __restrict__ C, int M, int N, int K) {
  __shared__ __align__(16) u16 As[4][8192];
  __shared__ __align__(16) u16 Bs[4][8192];
  int nwg = gridDim.x, q8 = nwg >> 3, bid = blockIdx.x;
  int nid = (bid & 7) * q8 + (bid >> 3);  // XCD-contiguous (nwg % 8 == 0)
  int mt = M >> 8;
  int m0 = (nid % mt) * 256, n0 = (nid / mt) * 256;
  int tid = threadIdx.x, wave = tid >> 6, lane = tid & 63;
  int wm = wave >> 2, wn = wave & 3;  // 2 x 4 wave grid
  int fr = lane & 15, fq = lane >> 4;

  // swizzled LDS read offsets (bytes within one 16KB tile), loop-invariant
  int a_off[8], b_off[4];
#pragma unroll
  for (int m = 0; m < 8; ++m) {
    int r = wm * 128 + m * 16 + fr;
    a_off[m] = r * 64 + ((fq ^ ((r ^ (r >> 2)) & 3)) << 4);
  }
#pragma unroll
  for (int n = 0; n < 4; ++n) {
    int r = wn * 64 + n * 16 + fr;
    b_off[n] = r * 64 + ((fq ^ ((r ^ (r >> 2)) & 3)) << 4);
  }

  // staging source (pre-swizzled slot): issue0 rows 0..127, issue1 rows 128..255
  int srow = tid >> 2, sslot = tid & 3;
  int r1 = 128 + srow;
  int sc0 = sslot ^ ((srow ^ (srow >> 2)) & 3);
  int sc1 = sslot ^ ((r1 ^ (r1 >> 2)) & 3);
  const u16* aS0 = A + (size_t)(m0 + srow) * K + sc0 * 8;
  const u16* aS1 = A + (size_t)(m0 + r1) * K + sc1 * 8;
  const u16* bS0 = Bt + (size_t)(n0 + srow) * K + sc0 * 8;
  const u16* bS1 = Bt + (size_t)(n0 + r1) * K + sc1 * 8;
  int wofs = wave * 512;  // wave's 1KB chunk (u16 units) within an 8KB issue region

  f32x4 acc[8][4] = {};

  auto stage = [&](int j) {
    int b = j & 3;
    int kb = j * 32;
    stage16(aS0 + kb, &As[b][wofs]);
    stage16(aS1 + kb, &As[b][4096 + wofs]);
    stage16(bS0 + kb, &Bs[b][wofs]);
    stage16(bS1 + kb, &Bs[b][4096 + wofs]);
  };
  auto compute = [&](int j) {
    int b = j & 3;
    const char* Ab = (const char*)&As[b][0];
    const char* Bb = (const char*)&Bs[b][0];
    bf16x8 af[8], bf[4];
#pragma unroll
    for (int m = 0; m < 8; ++m) af[m] = *(const bf16x8*)(Ab + a_off[m]);
#pragma unroll
    for (int n = 0; n < 4; ++n) bf[n] = *(const bf16x8*)(Bb + b_off[n]);
    __builtin_amdgcn_s_setprio(1);
#pragma unroll
    for (int m = 0; m < 8; ++m)
#pragma unroll
      for (int n = 0; n < 4; ++n)
        acc[m][n] = mfma16(af[m], bf[n], acc[m][n]);
    __builtin_amdgcn_s_setprio(0);
  };

  int NT = K >> 5;  // 128
  stage(0); stage(1); stage(2);
  for (int j = 0; j < NT; ++j) {
    if (j + 3 < NT) {
      stage(j + 3);
      asm volatile("s_waitcnt vmcnt(12)" ::: "memory");  // tile j fully landed
    } else if (j + 2 < NT) {
      asm volatile("s_waitcnt vmcnt(8)" ::: "memory");
    } else if (j + 1 < NT) {
      asm volatile("s_waitcnt vmcnt(4)" ::: "memory");
    } else {
      asm volatile("s_waitcnt vmcnt(0)" ::: "memory");
    }
    __builtin_amdgcn_s_barrier();          // all waves' tile-j portions visible
    __builtin_amdgcn_sched_barrier(0);
    compute(j);
    __builtin_amdgcn_s_barrier();          // all waves done reading buf[j&3]
  }

#pragma unroll
  for (int m = 0; m < 8; ++m)
#pragma unroll
    for (int n = 0; n < 4; ++n)
#pragma unroll
      for (int r = 0; r < 4; ++r) {
        int row = m0 + wm * 128 + m * 16 + fq * 4 + r;
        int col = n0 + wn * 64 + n * 16 + fr;
        storeC(&C[(size_t)row * N + col], acc[m][n][r]);
      }
}

// ---------------- RMSNorm + RoPE (Q pre-scaled by SM_SCALE) ----------------
__global__ __launch_bounds__(256) void normrope(u16* __restrict__ QKV,
                                                const float* __restrict__ qw,
                                                const float* __restrict__ kw) {
  int wq = threadIdx.x >> 6, lane = threadIdx.x & 63;
  int gid = blockIdx.x * 4 + wq;
  int token = gid / 40, head = gid % 40;
  int pos = token & (SEQ - 1);
  const float* wrow;
  int col;
  float sc;
  if (head < NH) { wrow = qw; col = head * HD; sc = SM_SCALE; }
  else           { wrow = kw; col = DMODEL + (head - NH) * HD; sc = 1.0f; }
  u16* row = QKV + (size_t)token * QKVN + col;
  ushort2 xv = *(const ushort2*)(row + 2 * lane);
  float x1 = bf2f(xv.x), x2 = bf2f(xv.y);
  float ssq = x1 * x1 + x2 * x2;
#pragma unroll
  for (int o = 32; o; o >>= 1) ssq += __shfl_xor(ssq, o, 64);
  float rms = rsqrtf(ssq * (1.0f / HD) + RMS_EPS);
  float y1 = x1 * rms * wrow[2 * lane] * sc;
  float y2 = x2 * rms * wrow[2 * lane + 1] * sc;
  float freq = exp2f((float)lane * -0.20762050593046014f);
  float ang = (float)pos * freq;
  float s, c;
  sincosf(ang, &s, &c);
  ushort2 ov;
  ov.x = f2bf(y1 * c - y2 * s);
  ov.y = f2bf(y1 * s + y2 * c);
  *(ushort2*)(row + 2 * lane) = ov;
}

// ---------------- 4-wave 32x32 swapped-QK^T flash attention (r8, proven) ----------------
__global__ __launch_bounds__(256, 2) void attn(const u16* __restrict__ QKV, u16* __restrict__ O) {
  int bid0 = blockIdx.x;
  int bid = (bid0 & 7) * 64 + (bid0 >> 3);
  int pairi = bid & 7, h = (bid >> 3) & 31, b = bid >> 8;
  int tid = threadIdx.x, wave = tid >> 6, lane = tid & 63;
  int qn = lane & 31, hi = lane >> 5;
  int hi4 = hi * 4, hi16 = hi * 16;
  int kvh = h >> 2;

  __shared__ __align__(16) u16 Ks[2][64 * 128];
  __shared__ __align__(16) u16 Vs[2][128 * 64];

  size_t tokb = (size_t)b * SEQ;
  const u16* Kg = QKV + tokb * QKVN + DMODEL + kvh * HD;
  const u16* Vg = Kg + NKV * HD;
  int srow = tid >> 4, sl = tid & 15;

  int kk0 = (qn & 7) << 4;
  int d0 = qn, d1 = 32 + qn, d2 = 64 + qn, d3 = 96 + qn;
  int vk0 = ((d0 ^ (d0 >> 3)) & 7) << 4;
  int vk1 = ((d1 ^ (d1 >> 3)) & 7) << 4;
  int vk2 = ((d2 ^ (d2 >> 3)) & 7) << 4;
  int vk3 = ((d3 ^ (d3 >> 3)) & 7) << 4;

  int4 vreg[4];
  auto loadV = [&](int kv0) {
#pragma unroll
    for (int i = 0; i < 4; ++i)
      vreg[i] = *(const int4*)(Vg + (size_t)(kv0 + i * 16 + srow) * QKVN + sl * 8);
  };
  auto stageK = [&](int buf, int kv0) {
#pragma unroll
    for (int i = 0; i < 4; ++i) {
      int row = i * 16 + srow;
      __builtin_amdgcn_global_load_lds(
          (const AS1 u32*)(Kg + (size_t)(kv0 + row) * QKVN + ((sl ^ (row & 7)) * 8)),
          (AS3 u32*)(&Ks[buf][0] + (i * 16 + wave * 4) * 128), 16, 0, 0);
    }
  };
  auto packV = [&](int buf) {
#pragma unroll
    for (int i = 0; i < 4; ++i) {
      int row = i * 16 + srow;
      int4 dvi = vreg[i];
      int4 dpi;
      dpi.x = __shfl_xor(dvi.x, 16, 64);
      dpi.y = __shfl_xor(dvi.y, 16, 64);
      dpi.z = __shfl_xor(dvi.z, 16, 64);
      dpi.w = __shfl_xor(dvi.w, 16, 64);
      if (((tid >> 4) & 1) == 0) {
        const u16* own = (const u16*)&dvi;
        const u16* par = (const u16*)&dpi;
#pragma unroll
        for (int j = 0; j < 8; ++j) {
          u32 wv = (u32)own[j] | ((u32)par[j] << 16);
          int d = sl * 8 + j;
          int vk = ((d ^ (d >> 3)) & 7) << 4;
          *(u32*)((char*)&Vs[buf][0] + d * 128 + ((2 * row) ^ vk)) = wv;
        }
      }
    }
  };

  for (int pass = 0; pass < 2; ++pass) {
    int chunk = pass ? (15 - pairi) : pairi;
    int chb = chunk * 128;
    int nt = (chunk + 1) * 2;
    int q0w = chb + wave * 32;
    int qabs = q0w + qn;
    int lim = chunk * 2 + (wave >> 1);
    int diag = q0w & ~63;

    bf16x8 qf[8];
    {
      const u16* qp = QKV + (tokb + q0w + qn) * QKVN + h * HD;
#pragma unroll
      for (int d = 0; d < 8; ++d) qf[d] = *(const bf16x8*)(qp + d * 16 + hi * 8);
    }

    f32x16 o0 = {}, o1 = {}, o2 = {}, o3 = {};
    float mrow = NEG_INF, lsum = 0.f;

    auto tile = [&](int kv0, const u16* Kl, const u16* Vl) {
      f32x16 p0v = {}, p1v = {};
      {
        const char* kb0 = (const char*)Kl + qn * 256;
        const char* kb1 = (const char*)Kl + (32 + qn) * 256;
        __builtin_amdgcn_s_setprio(1);
#pragma unroll
        for (int d = 0; d < 8; ++d) {
          bf16x8 k0 = *(const bf16x8*)(kb0 + ((d * 32 + hi16) ^ kk0));
          bf16x8 k1 = *(const bf16x8*)(kb1 + ((d * 32 + hi16) ^ kk0));
          p0v = mfma32(k0, qf[d], p0v);
          p1v = mfma32(k1, qf[d], p1v);
        }
        __builtin_amdgcn_s_setprio(0);
      }
      if (kv0 == diag) {
#pragma unroll
        for (int r = 0; r < 16; ++r) {
          int kva = kv0 + (r & 3) + 8 * (r >> 2) + hi4;
          if (kva > qabs) p0v[r] = NEG_INF;
          if (kva + 32 > qabs) p1v[r] = NEG_INF;
        }
      }
      float tmax = NEG_INF;
#pragma unroll
      for (int r = 0; r < 16; ++r) tmax = fmaxf(tmax, fmaxf(p0v[r], p1v[r]));
      tmax = fmaxf(tmax, __shfl_xor(tmax, 32, 64));
      if (!__all(tmax <= mrow + 8.0f)) {
        float nm = fmaxf(mrow, tmax);
        float corr = __expf(mrow - nm);
        mrow = nm;
        lsum *= corr;
#pragma unroll
        for (int r = 0; r < 16; ++r) {
          int srcl = (r & 3) + 8 * (r >> 2) + hi4;
          float cr = __shfl(corr, srcl, 64);
          o0[r] *= cr; o1[r] *= cr; o2[r] *= cr; o3[r] *= cr;
        }
      }
      float rs = 0.f;
#pragma unroll
      for (int r = 0; r < 16; ++r) {
        p0v[r] = __expf(p0v[r] - mrow);
        p1v[r] = __expf(p1v[r] - mrow);
        rs += p0v[r] + p1v[r];
      }
      rs += __shfl_xor(rs, 32, 64);
      lsum += rs;

      auto pv = [&](const f32x16& pk, int kvs) {
#pragma unroll
        for (int e = 0; e < 2; ++e) {
          u32 A = packbf(pk[e * 8 + 0], pk[e * 8 + 1]);
          u32 Bw = packbf(pk[e * 8 + 2], pk[e * 8 + 3]);
          u32 C = packbf(pk[e * 8 + 4], pk[e * 8 + 5]);
          u32 Dw = packbf(pk[e * 8 + 6], pk[e * 8 + 7]);
          u32 sA = __shfl_xor(A, 32, 64), sC = __shfl_xor(C, 32, 64);
          u32 sB = __shfl_xor(Bw, 32, 64), sD = __shfl_xor(Dw, 32, 64);
          union { u32 w[4]; bf16x8 v; } fr;
          fr.w[0] = hi ? sC : A;
          fr.w[1] = hi ? sD : Bw;
          fr.w[2] = hi ? C : sA;
          fr.w[3] = hi ? Dw : sB;
          int off = (kvs * 2 + e) * 32 + hi16;
          __builtin_amdgcn_s_setprio(1);
          o0 = mfma32(fr.v, *(const bf16x8*)((const char*)Vl + d0 * 128 + (off ^ vk0)), o0);
          o1 = mfma32(fr.v, *(const bf16x8*)((const char*)Vl + d1 * 128 + (off ^ vk1)), o1);
          o2 = mfma32(fr.v, *(const bf16x8*)((const char*)Vl + d2 * 128 + (off ^ vk2)), o2);
          o3 = mfma32(fr.v, *(const bf16x8*)((const char*)Vl + d3 * 128 + (off ^ vk3)), o3);
          __builtin_amdgcn_s_setprio(0);
        }
      };
      pv(p0v, 0);
      pv(p1v, 1);
    };

    loadV(0);
    stageK(0, 0);
    packV(0);
    __syncthreads();

    for (int t = 0; t < nt; ++t) {
      int cur = t & 1, nxt = cur ^ 1;
      bool more = (t + 1) < nt;
      if (more) {
        loadV((t + 1) * 64);
        stageK(nxt, (t + 1) * 64);
      }
      if (t <= lim) tile(t * 64, &Ks[cur][0], &Vs[cur][0]);
      if (more) packV(nxt);
      __syncthreads();
    }

#pragma unroll
    for (int r = 0; r < 16; ++r) {
      int ql = (r & 3) + 8 * (r >> 2) + hi4;
      float ls = __shfl(lsum, ql, 64);
      float inv = 1.0f / ls;
      size_t base = (tokb + chb + wave * 32 + ql) * (size_t)DMODEL + h * HD + qn;
      O[base] = f2bf(o0[r] * inv);
      O[base + 32] = f2bf(o1[r] * inv);
      O[base + 64] = f2bf(o2[r] * inv);
      O[base + 96] = f2bf(o3[r] * inv);
    }
  }
}

extern "C" void kernel_launch(void* const* d_in, const int* in_sizes, int n_in,
                              void* d_out, int out_size, void* d_ws, size_t ws_size,
                              hipStream_t stream) {
  const float* x  = (const float*)d_in[0];
  const float* Wq = (const float*)d_in[1];
  const float* Wk = (const float*)d_in[2];
  const float* Wv = (const float*)d_in[3];
  const float* Wo = (const float*)d_in[4];
  const float* qw = (const float*)d_in[5];
  const float* kw = (const float*)d_in[6];
  float* out = (float*)d_out;

  // Workspace (128 MiB):
  //   [0,   32M)  xb (bf16 x)  -- dead after GEMM1 -> reused as Wot
  //   [32M, 64M)  AO (attn out; region dead after GEMM1)
  //   [32M, 80M)  Wqkvt        -- dead after GEMM1
  //   [80M, 128M) QKVb
  char* ws = (char*)d_ws;
  u16* xb    = (u16*)(ws);
  u16* Wqkvt = (u16*)(ws + 33554432);
  u16* QKVb  = (u16*)(ws + 83886080);
  u16* Wot   = xb;
  u16* AO    = Wqkvt;

  cvt_f32_bf16<<<2048, 256, 0, stream>>>(x, xb, (2 * SEQ * DMODEL) / 4);
  dim3 tb(32, 8);
  tconv<<<dim3(DMODEL / 32, DMODEL / 32), tb, 0, stream>>>(Wq, Wqkvt, DMODEL, 0);
  tconv<<<dim3((NKV * HD) / 32, DMODEL / 32), tb, 0, stream>>>(Wk, Wqkvt, NKV * HD, DMODEL);
  tconv<<<dim3((NKV * HD) / 32, DMODEL / 32), tb, 0, stream>>>(Wv, Wqkvt, NKV * HD, DMODEL + NKV * HD);

  gemm256<u16><<<(4096 / 256) * (QKVN / 256), 512, 0, stream>>>(xb, Wqkvt, QKVb, 4096, QKVN, DMODEL);
  normrope<<<(4096 * 40) / 4, 256, 0, stream>>>(QKVb, qw, kw);

  tconv<<<dim3(DMODEL / 32, DMODEL / 32), tb, 0, stream>>>(Wo, Wot, DMODEL, 0);
  attn<<<512, 256, 0, stream>>>(QKVb, AO);
  gemm256<float><<<(4096 / 256) * (DMODEL / 256), 512, 0, stream>>>(AO, Wot, out, 4096, DMODEL, DMODEL);
}

// Round 10
// 633.749 us; speedup vs baseline: 1.1170x; 1.1170x over previous
//
#include <hip/hip_runtime.h>

typedef unsigned short u16;
typedef unsigned int u32;
typedef __attribute__((ext_vector_type(8))) short bf16x8;
typedef __attribute__((ext_vector_type(4))) float f32x4;
typedef __attribute__((ext_vector_type(16))) float f32x16;

#define NH 32
#define NKV 8
#define HD 128
#define SEQ 2048
#define DMODEL 4096
#define QKVN 6144
#define RMS_EPS 1e-6f
#define SM_SCALE 0.08838834764831845f
#define NEG_INF -1e30f

#define AS1 __attribute__((address_space(1)))
#define AS3 __attribute__((address_space(3)))

__device__ __forceinline__ u16 f2bf(float f) {
  unsigned int u = __float_as_uint(f);
  u += 0x7FFFu + ((u >> 16) & 1u);
  return (u16)(u >> 16);
}
__device__ __forceinline__ float bf2f(u16 b) {
  return __uint_as_float(((unsigned int)b) << 16);
}
__device__ __forceinline__ u32 packbf(float lo, float hi) {
  u32 a = __float_as_uint(lo) + 0x8000u;
  u32 b = __float_as_uint(hi) + 0x8000u;
  return __builtin_amdgcn_perm(b, a, 0x07060302u);
}

__device__ __forceinline__ f32x4 mfma16(bf16x8 a, bf16x8 b, f32x4 c) {
  return __builtin_amdgcn_mfma_f32_16x16x32_bf16(a, b, c, 0, 0, 0);
}
__device__ __forceinline__ f32x16 mfma32(bf16x8 a, bf16x8 b, f32x16 c) {
  return __builtin_amdgcn_mfma_f32_32x32x16_bf16(a, b, c, 0, 0, 0);
}

__device__ __forceinline__ void stage16(const u16* g, u16* l) {
  __builtin_amdgcn_global_load_lds((const AS1 u32*)g, (AS3 u32*)l, 16, 0, 0);
}

// ---------------- convert x: f32 -> bf16 ----------------
__global__ __launch_bounds__(256) void cvt_f32_bf16(const float* __restrict__ in,
                                                    u16* __restrict__ out, int n4) {
  int stride = gridDim.x * blockDim.x;
  for (int i = blockIdx.x * blockDim.x + threadIdx.x; i < n4; i += stride) {
    float4 v = ((const float4*)in)[i];
    ushort4 o;
    o.x = f2bf(v.x); o.y = f2bf(v.y); o.z = f2bf(v.z); o.w = f2bf(v.w);
    ((ushort4*)out)[i] = o;
  }
}

// ---------------- transpose-convert W[K=4096][N] f32 -> Wt[rowoff+N][4096] bf16 ----------------
__global__ __launch_bounds__(256) void tconv(const float* __restrict__ W, u16* __restrict__ Wt,
                                             int N, int rowoff) {
  __shared__ float t[32][33];
  int n0 = blockIdx.x * 32, k0 = blockIdx.y * 32;
  int tx = threadIdx.x, ty = threadIdx.y;  // (32,8)
#pragma unroll
  for (int i = 0; i < 4; ++i)
    t[ty + i * 8][tx] = W[(size_t)(k0 + ty + i * 8) * N + n0 + tx];
  __syncthreads();
#pragma unroll
  for (int i = 0; i < 4; ++i)
    Wt[(size_t)(rowoff + n0 + ty + i * 8) * DMODEL + k0 + tx] = f2bf(t[tx][ty + i * 8]);
}

// ---------------- GEMM (m97 structure + T1 XCD swizzle + T5, PROVEN r8) ----------------
__device__ __forceinline__ void storeC(u16* p, float v) { *p = f2bf(v); }
__device__ __forceinline__ void storeC(float* p, float v) { *p = v; }

template <typename OutT>
__global__ __launch_bounds__(256) void gemm_bt(const u16* __restrict__ A, const u16* __restrict__ Bt,
                                               OutT* __restrict__ C, int M, int N, int K) {
  __shared__ __align__(16) u16 As[128 * 32];
  __shared__ __align__(16) u16 Bs[128 * 32];
  int nwg = gridDim.x, q8 = nwg >> 3, bid = blockIdx.x;
  int nid = (bid & 7) * q8 + (bid >> 3);
  int mt = M >> 7;
  int m0 = (nid % mt) * 128, n0 = (nid / mt) * 128;
  int tid = threadIdx.x, wave = tid >> 6, lane = tid & 63;
  int wm = (wave >> 1) * 64, wn = (wave & 1) * 64;
  f32x4 acc[4][4] = {};
  int srow = lane >> 2;
  int scol = (lane & 3) * 8;
  int fr = lane & 15, fq = lane >> 4;

  for (int kb = 0; kb < K; kb += 32) {
    __syncthreads();
#pragma unroll
    for (int c = 0; c < 2; ++c) {
      int chunk = wave * 2 + c;
      int row = chunk * 16 + srow;
      stage16(A + (size_t)(m0 + row) * K + kb + scol, As + chunk * 512);
      stage16(Bt + (size_t)(n0 + row) * K + kb + scol, Bs + chunk * 512);
    }
    __syncthreads();
    bf16x8 af[4], bfv[4];
#pragma unroll
    for (int i = 0; i < 4; ++i) af[i] = *(const bf16x8*)&As[(wm + i * 16 + fr) * 32 + fq * 8];
#pragma unroll
    for (int j = 0; j < 4; ++j) bfv[j] = *(const bf16x8*)&Bs[(wn + j * 16 + fr) * 32 + fq * 8];
    __builtin_amdgcn_s_setprio(1);
#pragma unroll
    for (int i = 0; i < 4; ++i)
#pragma unroll
      for (int j = 0; j < 4; ++j)
        acc[i][j] = mfma16(af[i], bfv[j], acc[i][j]);
    __builtin_amdgcn_s_setprio(0);
  }
#pragma unroll
  for (int i = 0; i < 4; ++i)
#pragma unroll
    for (int j = 0; j < 4; ++j)
#pragma unroll
      for (int r = 0; r < 4; ++r) {
        int row = m0 + wm + i * 16 + fq * 4 + r;
        int col = n0 + wn + j * 16 + fr;
        storeC(&C[(size_t)row * N + col], acc[i][j][r]);
      }
}

// ---------------- RMSNorm + RoPE (Q pre-scaled by SM_SCALE) ----------------
__global__ __launch_bounds__(256) void normrope(u16* __restrict__ QKV,
                                                const float* __restrict__ qw,
                                                const float* __restrict__ kw) {
  int wq = threadIdx.x >> 6, lane = threadIdx.x & 63;
  int gid = blockIdx.x * 4 + wq;
  int token = gid / 40, head = gid % 40;
  int pos = token & (SEQ - 1);
  const float* wrow;
  int col;
  float sc;
  if (head < NH) { wrow = qw; col = head * HD; sc = SM_SCALE; }
  else           { wrow = kw; col = DMODEL + (head - NH) * HD; sc = 1.0f; }
  u16* row = QKV + (size_t)token * QKVN + col;
  ushort2 xv = *(const ushort2*)(row + 2 * lane);
  float x1 = bf2f(xv.x), x2 = bf2f(xv.y);
  float ssq = x1 * x1 + x2 * x2;
#pragma unroll
  for (int o = 32; o; o >>= 1) ssq += __shfl_xor(ssq, o, 64);
  float rms = rsqrtf(ssq * (1.0f / HD) + RMS_EPS);
  float y1 = x1 * rms * wrow[2 * lane] * sc;
  float y2 = x2 * rms * wrow[2 * lane + 1] * sc;
  float freq = exp2f((float)lane * -0.20762050593046014f);
  float ang = (float)pos * freq;
  float s, c;
  sincosf(ang, &s, &c);
  ushort2 ov;
  ov.x = f2bf(y1 * c - y2 * s);
  ov.y = f2bf(y1 * s + y2 * c);
  *(ushort2*)(row + 2 * lane) = ov;
}

// ---------------- 8-wave 32x32 swapped-QK^T flash attention ----------------
// Pure parameter scaling of the PROVEN r8 4-wave kernel: 512 thr = 8 waves x 32 q-rows
// = 256 q-rows/block; grid 256 (paired chunks {i,7-i} -> 36 tiles/block). K/V staging
// per q-row is HALVED vs r8. Same pipeline: prologue stage, dbuf, {loadV;stageK} ->
// compute -> packV -> one __syncthreads per tile. Same compute/layouts byte-for-byte.
__global__ __launch_bounds__(512, 2) void attn(const u16* __restrict__ QKV, u16* __restrict__ O) {
  // XCD swizzle: grid 256 = 8 * 32
  int bid0 = blockIdx.x;
  int bid = (bid0 & 7) * 32 + (bid0 >> 3);
  int pairi = bid & 3, h = (bid >> 2) & 31, b = bid >> 7;
  int tid = threadIdx.x, wave = tid >> 6, lane = tid & 63;
  int qn = lane & 31, hi = lane >> 5;
  int hi4 = hi * 4, hi16 = hi * 16;
  int kvh = h >> 2;

  __shared__ __align__(16) u16 Ks[2][64 * 128];
  __shared__ __align__(16) u16 Vs[2][128 * 64];

  size_t tokb = (size_t)b * SEQ;
  const u16* Kg = QKV + tokb * QKVN + DMODEL + kvh * HD;
  const u16* Vg = Kg + NKV * HD;
  int srow = tid >> 4, sl = tid & 15;  // srow 0..31

  int kk0 = (qn & 7) << 4;
  int d0 = qn, d1 = 32 + qn, d2 = 64 + qn, d3 = 96 + qn;
  int vk0 = ((d0 ^ (d0 >> 3)) & 7) << 4;
  int vk1 = ((d1 ^ (d1 >> 3)) & 7) << 4;
  int vk2 = ((d2 ^ (d2 >> 3)) & 7) << 4;
  int vk3 = ((d3 ^ (d3 >> 3)) & 7) << 4;

  int4 vreg[2];
  auto loadV = [&](int kv0) {
#pragma unroll
    for (int i = 0; i < 2; ++i)
      vreg[i] = *(const int4*)(Vg + (size_t)(kv0 + i * 32 + srow) * QKVN + sl * 8);
  };
  auto stageK = [&](int buf, int kv0) {
#pragma unroll
    for (int i = 0; i < 2; ++i) {
      int row = i * 32 + srow;
      __builtin_amdgcn_global_load_lds(
          (const AS1 u32*)(Kg + (size_t)(kv0 + row) * QKVN + ((sl ^ (row & 7)) * 8)),
          (AS3 u32*)(&Ks[buf][0] + (i * 32 + wave * 4) * 128), 16, 0, 0);
    }
  };
  auto packV = [&](int buf) {
#pragma unroll
    for (int i = 0; i < 2; ++i) {
      int row = i * 32 + srow;
      int4 dvi = vreg[i];
      int4 dpi;
      dpi.x = __shfl_xor(dvi.x, 16, 64);
      dpi.y = __shfl_xor(dvi.y, 16, 64);
      dpi.z = __shfl_xor(dvi.z, 16, 64);
      dpi.w = __shfl_xor(dvi.w, 16, 64);
      if (((tid >> 4) & 1) == 0) {  // even srow writes (kv, kv+1) word pairs
        const u16* own = (const u16*)&dvi;
        const u16* par = (const u16*)&dpi;
#pragma unroll
        for (int j = 0; j < 8; ++j) {
          u32 wv = (u32)own[j] | ((u32)par[j] << 16);
          int d = sl * 8 + j;
          int vk = ((d ^ (d >> 3)) & 7) << 4;
          *(u32*)((char*)&Vs[buf][0] + d * 128 + ((2 * row) ^ vk)) = wv;
        }
      }
    }
  };

  for (int pass = 0; pass < 2; ++pass) {
    int chunk = pass ? (7 - pairi) : pairi;
    int chb = chunk * 256;
    int nt = (chunk + 1) * 4;
    int q0w = chb + wave * 32;
    int qabs = q0w + qn;
    int lim = chunk * 4 + (wave >> 1);
    int diag = q0w & ~63;

    bf16x8 qf[8];
    {
      const u16* qp = QKV + (tokb + q0w + qn) * QKVN + h * HD;
#pragma unroll
      for (int d = 0; d < 8; ++d) qf[d] = *(const bf16x8*)(qp + d * 16 + hi * 8);
    }

    f32x16 o0 = {}, o1 = {}, o2 = {}, o3 = {};
    float mrow = NEG_INF, lsum = 0.f;

    auto tile = [&](int kv0, const u16* Kl, const u16* Vl) {
      f32x16 p0v = {}, p1v = {};
      {
        const char* kb0 = (const char*)Kl + qn * 256;
        const char* kb1 = (const char*)Kl + (32 + qn) * 256;
        __builtin_amdgcn_s_setprio(1);
#pragma unroll
        for (int d = 0; d < 8; ++d) {
          bf16x8 k0 = *(const bf16x8*)(kb0 + ((d * 32 + hi16) ^ kk0));
          bf16x8 k1 = *(const bf16x8*)(kb1 + ((d * 32 + hi16) ^ kk0));
          p0v = mfma32(k0, qf[d], p0v);
          p1v = mfma32(k1, qf[d], p1v);
        }
        __builtin_amdgcn_s_setprio(0);
      }
      if (kv0 == diag) {
#pragma unroll
        for (int r = 0; r < 16; ++r) {
          int kva = kv0 + (r & 3) + 8 * (r >> 2) + hi4;
          if (kva > qabs) p0v[r] = NEG_INF;
          if (kva + 32 > qabs) p1v[r] = NEG_INF;
        }
      }
      float tmax = NEG_INF;
#pragma unroll
      for (int r = 0; r < 16; ++r) tmax = fmaxf(tmax, fmaxf(p0v[r], p1v[r]));
      tmax = fmaxf(tmax, __shfl_xor(tmax, 32, 64));
      if (!__all(tmax <= mrow + 8.0f)) {
        float nm = fmaxf(mrow, tmax);
        float corr = __expf(mrow - nm);
        mrow = nm;
        lsum *= corr;
#pragma unroll
        for (int r = 0; r < 16; ++r) {
          int srcl = (r & 3) + 8 * (r >> 2) + hi4;
          float cr = __shfl(corr, srcl, 64);
          o0[r] *= cr; o1[r] *= cr; o2[r] *= cr; o3[r] *= cr;
        }
      }
      float rs = 0.f;
#pragma unroll
      for (int r = 0; r < 16; ++r) {
        p0v[r] = __expf(p0v[r] - mrow);
        p1v[r] = __expf(p1v[r] - mrow);
        rs += p0v[r] + p1v[r];
      }
      rs += __shfl_xor(rs, 32, 64);
      lsum += rs;

      auto pv = [&](const f32x16& pk, int kvs) {
#pragma unroll
        for (int e = 0; e < 2; ++e) {
          u32 A = packbf(pk[e * 8 + 0], pk[e * 8 + 1]);
          u32 Bw = packbf(pk[e * 8 + 2], pk[e * 8 + 3]);
          u32 C = packbf(pk[e * 8 + 4], pk[e * 8 + 5]);
          u32 Dw = packbf(pk[e * 8 + 6], pk[e * 8 + 7]);
          u32 sA = __shfl_xor(A, 32, 64), sC = __shfl_xor(C, 32, 64);
          u32 sB = __shfl_xor(Bw, 32, 64), sD = __shfl_xor(Dw, 32, 64);
          union { u32 w[4]; bf16x8 v; } fr;
          fr.w[0] = hi ? sC : A;
          fr.w[1] = hi ? sD : Bw;
          fr.w[2] = hi ? C : sA;
          fr.w[3] = hi ? Dw : sB;
          int off = (kvs * 2 + e) * 32 + hi16;
          __builtin_amdgcn_s_setprio(1);
          o0 = mfma32(fr.v, *(const bf16x8*)((const char*)Vl + d0 * 128 + (off ^ vk0)), o0);
          o1 = mfma32(fr.v, *(const bf16x8*)((const char*)Vl + d1 * 128 + (off ^ vk1)), o1);
          o2 = mfma32(fr.v, *(const bf16x8*)((const char*)Vl + d2 * 128 + (off ^ vk2)), o2);
          o3 = mfma32(fr.v, *(const bf16x8*)((const char*)Vl + d3 * 128 + (off ^ vk3)), o3);
          __builtin_amdgcn_s_setprio(0);
        }
      };
      pv(p0v, 0);
      pv(p1v, 1);
    };

    loadV(0);
    stageK(0, 0);
    packV(0);
    __syncthreads();

    for (int t = 0; t < nt; ++t) {
      int cur = t & 1, nxt = cur ^ 1;
      bool more = (t + 1) < nt;
      if (more) {
        loadV((t + 1) * 64);
        stageK(nxt, (t + 1) * 64);
      }
      if (t <= lim) tile(t * 64, &Ks[cur][0], &Vs[cur][0]);
      if (more) packV(nxt);
      __syncthreads();
    }

#pragma unroll
    for (int r = 0; r < 16; ++r) {
      int ql = (r & 3) + 8 * (r >> 2) + hi4;
      float ls = __shfl(lsum, ql, 64);
      float inv = 1.0f / ls;
      size_t base = (tokb + chb + wave * 32 + ql) * (size_t)DMODEL + h * HD + qn;
      O[base] = f2bf(o0[r] * inv);
      O[base + 32] = f2bf(o1[r] * inv);
      O[base + 64] = f2bf(o2[r] * inv);
      O[base + 96] = f2bf(o3[r] * inv);
    }
  }
}

extern "C" void kernel_launch(void* const* d_in, const int* in_sizes, int n_in,
                              void* d_out, int out_size, void* d_ws, size_t ws_size,
                              hipStream_t stream) {
  const float* x  = (const float*)d_in[0];
  const float* Wq = (const float*)d_in[1];
  const float* Wk = (const float*)d_in[2];
  const float* Wv = (const float*)d_in[3];
  const float* Wo = (const float*)d_in[4];
  const float* qw = (const float*)d_in[5];
  const float* kw = (const float*)d_in[6];
  float* out = (float*)d_out;

  // Workspace (128 MiB):
  //   [0,   32M)  xb (bf16 x)  -- dead after GEMM1 -> reused as Wot
  //   [32M, 64M)  AO (attn out; region dead after GEMM1)
  //   [32M, 80M)  Wqkvt        -- dead after GEMM1
  //   [80M, 128M) QKVb
  char* ws = (char*)d_ws;
  u16* xb    = (u16*)(ws);
  u16* Wqkvt = (u16*)(ws + 33554432);
  u16* QKVb  = (u16*)(ws + 83886080);
  u16* Wot   = xb;
  u16* AO    = Wqkvt;

  cvt_f32_bf16<<<2048, 256, 0, stream>>>(x, xb, (2 * SEQ * DMODEL) / 4);
  dim3 tb(32, 8);
  tconv<<<dim3(DMODEL / 32, DMODEL / 32), tb, 0, stream>>>(Wq, Wqkvt, DMODEL, 0);
  tconv<<<dim3((NKV * HD) / 32, DMODEL / 32), tb, 0, stream>>>(Wk, Wqkvt, NKV * HD, DMODEL);
  tconv<<<dim3((NKV * HD) / 32, DMODEL / 32), tb, 0, stream>>>(Wv, Wqkvt, NKV * HD, DMODEL + NKV * HD);

  gemm_bt<u16><<<(4096 / 128) * (QKVN / 128), 256, 0, stream>>>(xb, Wqkvt, QKVb, 4096, QKVN, DMODEL);
  normrope<<<(4096 * 40) / 4, 256, 0, stream>>>(QKVb, qw, kw);

  tconv<<<dim3(DMODEL / 32, DMODEL / 32), tb, 0, stream>>>(Wo, Wot, DMODEL, 0);
  attn<<<256, 512, 0, stream>>>(QKVb, AO);
  gemm_bt<float><<<(4096 / 128) * (DMODEL / 128), 256, 0, stream>>>(AO, Wot, out, 4096, DMODEL, DMODEL);
}

// Round 11
// 592.691 us; speedup vs baseline: 1.1944x; 1.0693x over previous
//
#include <hip/hip_runtime.h>

typedef unsigned short u16;
typedef unsigned int u32;
typedef __attribute__((ext_vector_type(8))) short bf16x8;
typedef __attribute__((ext_vector_type(4))) float f32x4;
typedef __attribute__((ext_vector_type(16))) float f32x16;

#define NH 32
#define NKV 8
#define HD 128
#define SEQ 2048
#define DMODEL 4096
#define QKVN 6144
#define RMS_EPS 1e-6f
#define SM_SCALE 0.08838834764831845f
#define NEG_INF -1e30f

#define AS1 __attribute__((address_space(1)))
#define AS3 __attribute__((address_space(3)))

__device__ __forceinline__ u16 f2bf(float f) {
  unsigned int u = __float_as_uint(f);
  u += 0x7FFFu + ((u >> 16) & 1u);
  return (u16)(u >> 16);
}
__device__ __forceinline__ float bf2f(u16 b) {
  return __uint_as_float(((unsigned int)b) << 16);
}
__device__ __forceinline__ u32 packbf(float lo, float hi) {
  u32 a = __float_as_uint(lo) + 0x8000u;
  u32 b = __float_as_uint(hi) + 0x8000u;
  return __builtin_amdgcn_perm(b, a, 0x07060302u);
}

__device__ __forceinline__ f32x4 mfma16(bf16x8 a, bf16x8 b, f32x4 c) {
  return __builtin_amdgcn_mfma_f32_16x16x32_bf16(a, b, c, 0, 0, 0);
}
__device__ __forceinline__ f32x16 mfma32(bf16x8 a, bf16x8 b, f32x16 c) {
  return __builtin_amdgcn_mfma_f32_32x32x16_bf16(a, b, c, 0, 0, 0);
}

__device__ __forceinline__ void stage16(const u16* g, u16* l) {
  __builtin_amdgcn_global_load_lds((const AS1 u32*)g, (AS3 u32*)l, 16, 0, 0);
}

// ---------------- convert x: f32 -> bf16 ----------------
__global__ __launch_bounds__(256) void cvt_f32_bf16(const float* __restrict__ in,
                                                    u16* __restrict__ out, int n4) {
  int stride = gridDim.x * blockDim.x;
  for (int i = blockIdx.x * blockDim.x + threadIdx.x; i < n4; i += stride) {
    float4 v = ((const float4*)in)[i];
    ushort4 o;
    o.x = f2bf(v.x); o.y = f2bf(v.y); o.z = f2bf(v.z); o.w = f2bf(v.w);
    ((ushort4*)out)[i] = o;
  }
}

// ---------------- transpose-convert W[K=4096][N] f32 -> Wt[rowoff+N][4096] bf16 ----------------
__global__ __launch_bounds__(256) void tconv(const float* __restrict__ W, u16* __restrict__ Wt,
                                             int N, int rowoff) {
  __shared__ float t[32][33];
  int n0 = blockIdx.x * 32, k0 = blockIdx.y * 32;
  int tx = threadIdx.x, ty = threadIdx.y;  // (32,8)
#pragma unroll
  for (int i = 0; i < 4; ++i)
    t[ty + i * 8][tx] = W[(size_t)(k0 + ty + i * 8) * N + n0 + tx];
  __syncthreads();
#pragma unroll
  for (int i = 0; i < 4; ++i)
    Wt[(size_t)(rowoff + n0 + ty + i * 8) * DMODEL + k0 + tx] = f2bf(t[tx][ty + i * 8]);
}

// ---------------- GEMM: m97 skeleton, BK=64, T2 swizzle, T1 XCD swizzle, T5 ----------------
// 128x128 tile, 4 waves, 2-barrier loop (64 iters over K=4096). LDS 32KB:
// As/Bs[128][64] u16, 128B rows, 16B-slot swizzle key row&7 (pre-swizzled global
// source -> linear LDS dest; reads XOR the same key -> <=2-way conflicts).
// Per iter: 8x stage16, 2 half-steps of {8 ds_read_b128, 16 MFMA}.
__device__ __forceinline__ void storeC(u16* p, float v) { *p = f2bf(v); }
__device__ __forceinline__ void storeC(float* p, float v) { *p = v; }

template <typename OutT>
__global__ __launch_bounds__(256) void gemm_bt(const u16* __restrict__ A, const u16* __restrict__ Bt,
                                               OutT* __restrict__ C, int M, int N, int K) {
  __shared__ __align__(16) u16 As[128 * 64];
  __shared__ __align__(16) u16 Bs[128 * 64];
  int nwg = gridDim.x, q8 = nwg >> 3, bid = blockIdx.x;
  int nid = (bid & 7) * q8 + (bid >> 3);
  int mt = M >> 7;
  int m0 = (nid % mt) * 128, n0 = (nid / mt) * 128;
  int tid = threadIdx.x, wave = tid >> 6, lane = tid & 63;
  int wm = (wave >> 1) * 64, wn = (wave & 1) * 64;
  f32x4 acc[4][4] = {};
  int fr = lane & 15, fq = lane >> 4;

  // staging: issue i covers rows i*32..i*32+31; thread row = i*32 + (tid>>3),
  // source 16B-slot = (tid&7) ^ ((tid>>3)&7); LDS dest wave-uniform.
  int srow_ = tid >> 3;                 // 0..31
  int scol = ((tid & 7) ^ (srow_ & 7)) * 8;  // u16 col in row (pre-swizzled)
  const u16* aSrc = A + (size_t)(m0 + srow_) * K + scol;
  const u16* bSrc = Bt + (size_t)(n0 + srow_) * K + scol;
  size_t rstride = (size_t)32 * K;
  u16* ldst = (u16*)((char*)nullptr);  // unused
  int dofs = wave * 512;               // u16; + i*2048 per issue

  // fragment read offsets: row = wm|wn + i*16 + fr, key = fr&7,
  // slot = (ks*4 + fq) ^ (fr&7); byte = row*128 + slot*16
  int akey = (fr & 7);

  for (int kb = 0; kb < K; kb += 64) {
    __syncthreads();
#pragma unroll
    for (int i = 0; i < 4; ++i) {
      stage16(aSrc + i * rstride + kb, As + i * 2048 + dofs);
      stage16(bSrc + i * rstride + kb, Bs + i * 2048 + dofs);
    }
    __syncthreads();
#pragma unroll
    for (int ks = 0; ks < 2; ++ks) {
      bf16x8 af[4], bfv[4];
      int slot = (ks * 4 + fq) ^ akey;
#pragma unroll
      for (int i = 0; i < 4; ++i)
        af[i] = *(const bf16x8*)((const char*)As + (wm + i * 16 + fr) * 128 + slot * 16);
#pragma unroll
      for (int j = 0; j < 4; ++j)
        bfv[j] = *(const bf16x8*)((const char*)Bs + (wn + j * 16 + fr) * 128 + slot * 16);
      __builtin_amdgcn_s_setprio(1);
#pragma unroll
      for (int i = 0; i < 4; ++i)
#pragma unroll
        for (int j = 0; j < 4; ++j)
          acc[i][j] = mfma16(af[i], bfv[j], acc[i][j]);
      __builtin_amdgcn_s_setprio(0);
    }
  }
#pragma unroll
  for (int i = 0; i < 4; ++i)
#pragma unroll
    for (int j = 0; j < 4; ++j)
#pragma unroll
      for (int r = 0; r < 4; ++r) {
        int row = m0 + wm + i * 16 + fq * 4 + r;
        int col = n0 + wn + j * 16 + fr;
        storeC(&C[(size_t)row * N + col], acc[i][j][r]);
      }
}

// ---------------- RMSNorm + RoPE (Q pre-scaled by SM_SCALE) ----------------
__global__ __launch_bounds__(256) void normrope(u16* __restrict__ QKV,
                                                const float* __restrict__ qw,
                                                const float* __restrict__ kw) {
  int wq = threadIdx.x >> 6, lane = threadIdx.x & 63;
  int gid = blockIdx.x * 4 + wq;
  int token = gid / 40, head = gid % 40;
  int pos = token & (SEQ - 1);
  const float* wrow;
  int col;
  float sc;
  if (head < NH) { wrow = qw; col = head * HD; sc = SM_SCALE; }
  else           { wrow = kw; col = DMODEL + (head - NH) * HD; sc = 1.0f; }
  u16* row = QKV + (size_t)token * QKVN + col;
  ushort2 xv = *(const ushort2*)(row + 2 * lane);
  float x1 = bf2f(xv.x), x2 = bf2f(xv.y);
  float ssq = x1 * x1 + x2 * x2;
#pragma unroll
  for (int o = 32; o; o >>= 1) ssq += __shfl_xor(ssq, o, 64);
  float rms = rsqrtf(ssq * (1.0f / HD) + RMS_EPS);
  float y1 = x1 * rms * wrow[2 * lane] * sc;
  float y2 = x2 * rms * wrow[2 * lane + 1] * sc;
  float freq = exp2f((float)lane * -0.20762050593046014f);
  float ang = (float)pos * freq;
  float s, c;
  sincosf(ang, &s, &c);
  ushort2 ov;
  ov.x = f2bf(y1 * c - y2 * s);
  ov.y = f2bf(y1 * s + y2 * c);
  *(ushort2*)(row + 2 * lane) = ov;
}

// ---------------- 8-wave 32x32 swapped-QK^T flash attention (r10, proven) ----------------
__global__ __launch_bounds__(512, 2) void attn(const u16* __restrict__ QKV, u16* __restrict__ O) {
  // XCD swizzle: grid 256 = 8 * 32
  int bid0 = blockIdx.x;
  int bid = (bid0 & 7) * 32 + (bid0 >> 3);
  int pairi = bid & 3, h = (bid >> 2) & 31, b = bid >> 7;
  int tid = threadIdx.x, wave = tid >> 6, lane = tid & 63;
  int qn = lane & 31, hi = lane >> 5;
  int hi4 = hi * 4, hi16 = hi * 16;
  int kvh = h >> 2;

  __shared__ __align__(16) u16 Ks[2][64 * 128];
  __shared__ __align__(16) u16 Vs[2][128 * 64];

  size_t tokb = (size_t)b * SEQ;
  const u16* Kg = QKV + tokb * QKVN + DMODEL + kvh * HD;
  const u16* Vg = Kg + NKV * HD;
  int srow = tid >> 4, sl = tid & 15;  // srow 0..31

  int kk0 = (qn & 7) << 4;
  int d0 = qn, d1 = 32 + qn, d2 = 64 + qn, d3 = 96 + qn;
  int vk0 = ((d0 ^ (d0 >> 3)) & 7) << 4;
  int vk1 = ((d1 ^ (d1 >> 3)) & 7) << 4;
  int vk2 = ((d2 ^ (d2 >> 3)) & 7) << 4;
  int vk3 = ((d3 ^ (d3 >> 3)) & 7) << 4;

  int4 vreg[2];
  auto loadV = [&](int kv0) {
#pragma unroll
    for (int i = 0; i < 2; ++i)
      vreg[i] = *(const int4*)(Vg + (size_t)(kv0 + i * 32 + srow) * QKVN + sl * 8);
  };
  auto stageK = [&](int buf, int kv0) {
#pragma unroll
    for (int i = 0; i < 2; ++i) {
      int row = i * 32 + srow;
      __builtin_amdgcn_global_load_lds(
          (const AS1 u32*)(Kg + (size_t)(kv0 + row) * QKVN + ((sl ^ (row & 7)) * 8)),
          (AS3 u32*)(&Ks[buf][0] + (i * 32 + wave * 4) * 128), 16, 0, 0);
    }
  };
  auto packV = [&](int buf) {
#pragma unroll
    for (int i = 0; i < 2; ++i) {
      int row = i * 32 + srow;
      int4 dvi = vreg[i];
      int4 dpi;
      dpi.x = __shfl_xor(dvi.x, 16, 64);
      dpi.y = __shfl_xor(dvi.y, 16, 64);
      dpi.z = __shfl_xor(dvi.z, 16, 64);
      dpi.w = __shfl_xor(dvi.w, 16, 64);
      if (((tid >> 4) & 1) == 0) {
        const u16* own = (const u16*)&dvi;
        const u16* par = (const u16*)&dpi;
#pragma unroll
        for (int j = 0; j < 8; ++j) {
          u32 wv = (u32)own[j] | ((u32)par[j] << 16);
          int d = sl * 8 + j;
          int vk = ((d ^ (d >> 3)) & 7) << 4;
          *(u32*)((char*)&Vs[buf][0] + d * 128 + ((2 * row) ^ vk)) = wv;
        }
      }
    }
  };

  for (int pass = 0; pass < 2; ++pass) {
    int chunk = pass ? (7 - pairi) : pairi;
    int chb = chunk * 256;
    int nt = (chunk + 1) * 4;
    int q0w = chb + wave * 32;
    int qabs = q0w + qn;
    int lim = chunk * 4 + (wave >> 1);
    int diag = q0w & ~63;

    bf16x8 qf[8];
    {
      const u16* qp = QKV + (tokb + q0w + qn) * QKVN + h * HD;
#pragma unroll
      for (int d = 0; d < 8; ++d) qf[d] = *(const bf16x8*)(qp + d * 16 + hi * 8);
    }

    f32x16 o0 = {}, o1 = {}, o2 = {}, o3 = {};
    float mrow = NEG_INF, lsum = 0.f;

    auto tile = [&](int kv0, const u16* Kl, const u16* Vl) {
      f32x16 p0v = {}, p1v = {};
      {
        const char* kb0 = (const char*)Kl + qn * 256;
        const char* kb1 = (const char*)Kl + (32 + qn) * 256;
        __builtin_amdgcn_s_setprio(1);
#pragma unroll
        for (int d = 0; d < 8; ++d) {
          bf16x8 k0 = *(const bf16x8*)(kb0 + ((d * 32 + hi16) ^ kk0));
          bf16x8 k1 = *(const bf16x8*)(kb1 + ((d * 32 + hi16) ^ kk0));
          p0v = mfma32(k0, qf[d], p0v);
          p1v = mfma32(k1, qf[d], p1v);
        }
        __builtin_amdgcn_s_setprio(0);
      }
      if (kv0 == diag) {
#pragma unroll
        for (int r = 0; r < 16; ++r) {
          int kva = kv0 + (r & 3) + 8 * (r >> 2) + hi4;
          if (kva > qabs) p0v[r] = NEG_INF;
          if (kva + 32 > qabs) p1v[r] = NEG_INF;
        }
      }
      float tmax = NEG_INF;
#pragma unroll
      for (int r = 0; r < 16; ++r) tmax = fmaxf(tmax, fmaxf(p0v[r], p1v[r]));
      tmax = fmaxf(tmax, __shfl_xor(tmax, 32, 64));
      if (!__all(tmax <= mrow + 8.0f)) {
        float nm = fmaxf(mrow, tmax);
        float corr = __expf(mrow - nm);
        mrow = nm;
        lsum *= corr;
#pragma unroll
        for (int r = 0; r < 16; ++r) {
          int srcl = (r & 3) + 8 * (r >> 2) + hi4;
          float cr = __shfl(corr, srcl, 64);
          o0[r] *= cr; o1[r] *= cr; o2[r] *= cr; o3[r] *= cr;
        }
      }
      float rs = 0.f;
#pragma unroll
      for (int r = 0; r < 16; ++r) {
        p0v[r] = __expf(p0v[r] - mrow);
        p1v[r] = __expf(p1v[r] - mrow);
        rs += p0v[r] + p1v[r];
      }
      rs += __shfl_xor(rs, 32, 64);
      lsum += rs;

      auto pv = [&](const f32x16& pk, int kvs) {
#pragma unroll
        for (int e = 0; e < 2; ++e) {
          u32 A = packbf(pk[e * 8 + 0], pk[e * 8 + 1]);
          u32 Bw = packbf(pk[e * 8 + 2], pk[e * 8 + 3]);
          u32 C = packbf(pk[e * 8 + 4], pk[e * 8 + 5]);
          u32 Dw = packbf(pk[e * 8 + 6], pk[e * 8 + 7]);
          u32 sA = __shfl_xor(A, 32, 64), sC = __shfl_xor(C, 32, 64);
          u32 sB = __shfl_xor(Bw, 32, 64), sD = __shfl_xor(Dw, 32, 64);
          union { u32 w[4]; bf16x8 v; } fr;
          fr.w[0] = hi ? sC : A;
          fr.w[1] = hi ? sD : Bw;
          fr.w[2] = hi ? C : sA;
          fr.w[3] = hi ? Dw : sB;
          int off = (kvs * 2 + e) * 32 + hi16;
          __builtin_amdgcn_s_setprio(1);
          o0 = mfma32(fr.v, *(const bf16x8*)((const char*)Vl + d0 * 128 + (off ^ vk0)), o0);
          o1 = mfma32(fr.v, *(const bf16x8*)((const char*)Vl + d1 * 128 + (off ^ vk1)), o1);
          o2 = mfma32(fr.v, *(const bf16x8*)((const char*)Vl + d2 * 128 + (off ^ vk2)), o2);
          o3 = mfma32(fr.v, *(const bf16x8*)((const char*)Vl + d3 * 128 + (off ^ vk3)), o3);
          __builtin_amdgcn_s_setprio(0);
        }
      };
      pv(p0v, 0);
      pv(p1v, 1);
    };

    loadV(0);
    stageK(0, 0);
    packV(0);
    __syncthreads();

    for (int t = 0; t < nt; ++t) {
      int cur = t & 1, nxt = cur ^ 1;
      bool more = (t + 1) < nt;
      if (more) {
        loadV((t + 1) * 64);
        stageK(nxt, (t + 1) * 64);
      }
      if (t <= lim) tile(t * 64, &Ks[cur][0], &Vs[cur][0]);
      if (more) packV(nxt);
      __syncthreads();
    }

#pragma unroll
    for (int r = 0; r < 16; ++r) {
      int ql = (r & 3) + 8 * (r >> 2) + hi4;
      float ls = __shfl(lsum, ql, 64);
      float inv = 1.0f / ls;
      size_t base = (tokb + chb + wave * 32 + ql) * (size_t)DMODEL + h * HD + qn;
      O[base] = f2bf(o0[r] * inv);
      O[base + 32] = f2bf(o1[r] * inv);
      O[base + 64] = f2bf(o2[r] * inv);
      O[base + 96] = f2bf(o3[r] * inv);
    }
  }
}

extern "C" void kernel_launch(void* const* d_in, const int* in_sizes, int n_in,
                              void* d_out, int out_size, void* d_ws, size_t ws_size,
                              hipStream_t stream) {
  const float* x  = (const float*)d_in[0];
  const float* Wq = (const float*)d_in[1];
  const float* Wk = (const float*)d_in[2];
  const float* Wv = (const float*)d_in[3];
  const float* Wo = (const float*)d_in[4];
  const float* qw = (const float*)d_in[5];
  const float* kw = (const float*)d_in[6];
  float* out = (float*)d_out;

  // Workspace (128 MiB):
  //   [0,   32M)  xb (bf16 x)  -- dead after GEMM1 -> reused as Wot
  //   [32M, 64M)  AO (attn out; region dead after GEMM1)
  //   [32M, 80M)  Wqkvt        -- dead after GEMM1
  //   [80M, 128M) QKVb
  char* ws = (char*)d_ws;
  u16* xb    = (u16*)(ws);
  u16* Wqkvt = (u16*)(ws + 33554432);
  u16* QKVb  = (u16*)(ws + 83886080);
  u16* Wot   = xb;
  u16* AO    = Wqkvt;

  cvt_f32_bf16<<<2048, 256, 0, stream>>>(x, xb, (2 * SEQ * DMODEL) / 4);
  dim3 tb(32, 8);
  tconv<<<dim3(DMODEL / 32, DMODEL / 32), tb, 0, stream>>>(Wq, Wqkvt, DMODEL, 0);
  tconv<<<dim3((NKV * HD) / 32, DMODEL / 32), tb, 0, stream>>>(Wk, Wqkvt, NKV * HD, DMODEL);
  tconv<<<dim3((NKV * HD) / 32, DMODEL / 32), tb, 0, stream>>>(Wv, Wqkvt, NKV * HD, DMODEL + NKV * HD);

  gemm_bt<u16><<<(4096 / 128) * (QKVN / 128), 256, 0, stream>>>(xb, Wqkvt, QKVb, 4096, QKVN, DMODEL);
  normrope<<<(4096 * 40) / 4, 256, 0, stream>>>(QKVb, qw, kw);

  tconv<<<dim3(DMODEL / 32, DMODEL / 32), tb, 0, stream>>>(Wo, Wot, DMODEL, 0);
  attn<<<256, 512, 0, stream>>>(QKVb, AO);
  gemm_bt<float><<<(4096 / 128) * (DMODEL / 128), 256, 0, stream>>>(AO, Wot, out, 4096, DMODEL, DMODEL);
}

// Round 12
// 588.646 us; speedup vs baseline: 1.2026x; 1.0069x over previous
//
#include <hip/hip_runtime.h>

typedef unsigned short u16;
typedef unsigned int u32;
typedef __attribute__((ext_vector_type(8))) short bf16x8;
typedef __attribute__((ext_vector_type(4))) float f32x4;
typedef __attribute__((ext_vector_type(16))) float f32x16;

#define NH 32
#define NKV 8
#define HD 128
#define SEQ 2048
#define DMODEL 4096
#define QKVN 6144
#define RMS_EPS 1e-6f
#define SM_SCALE 0.08838834764831845f
#define NEG_INF -1e30f

#define AS1 __attribute__((address_space(1)))
#define AS3 __attribute__((address_space(3)))

__device__ __forceinline__ u16 f2bf(float f) {
  unsigned int u = __float_as_uint(f);
  u += 0x7FFFu + ((u >> 16) & 1u);
  return (u16)(u >> 16);
}
__device__ __forceinline__ float bf2f(u16 b) {
  return __uint_as_float(((unsigned int)b) << 16);
}
__device__ __forceinline__ u32 packbf(float lo, float hi) {
  u32 a = __float_as_uint(lo) + 0x8000u;
  u32 b = __float_as_uint(hi) + 0x8000u;
  return __builtin_amdgcn_perm(b, a, 0x07060302u);
}

__device__ __forceinline__ f32x4 mfma16(bf16x8 a, bf16x8 b, f32x4 c) {
  return __builtin_amdgcn_mfma_f32_16x16x32_bf16(a, b, c, 0, 0, 0);
}
__device__ __forceinline__ f32x16 mfma32(bf16x8 a, bf16x8 b, f32x16 c) {
  return __builtin_amdgcn_mfma_f32_32x32x16_bf16(a, b, c, 0, 0, 0);
}

__device__ __forceinline__ void stage16(const u16* g, u16* l) {
  __builtin_amdgcn_global_load_lds((const AS1 u32*)g, (AS3 u32*)l, 16, 0, 0);
}

// ---------------- convert x: f32 -> bf16 ----------------
__global__ __launch_bounds__(256) void cvt_f32_bf16(const float* __restrict__ in,
                                                    u16* __restrict__ out, int n4) {
  int stride = gridDim.x * blockDim.x;
  for (int i = blockIdx.x * blockDim.x + threadIdx.x; i < n4; i += stride) {
    float4 v = ((const float4*)in)[i];
    ushort4 o;
    o.x = f2bf(v.x); o.y = f2bf(v.y); o.z = f2bf(v.z); o.w = f2bf(v.w);
    ((ushort4*)out)[i] = o;
  }
}

// ---------------- transpose-convert W[K=4096][N] f32 -> Wt[rowoff+N][4096] bf16 ----------------
__global__ __launch_bounds__(256) void tconv(const float* __restrict__ W, u16* __restrict__ Wt,
                                             int N, int rowoff) {
  __shared__ float t[32][33];
  int n0 = blockIdx.x * 32, k0 = blockIdx.y * 32;
  int tx = threadIdx.x, ty = threadIdx.y;  // (32,8)
#pragma unroll
  for (int i = 0; i < 4; ++i)
    t[ty + i * 8][tx] = W[(size_t)(k0 + ty + i * 8) * N + n0 + tx];
  __syncthreads();
#pragma unroll
  for (int i = 0; i < 4; ++i)
    Wt[(size_t)(rowoff + n0 + ty + i * 8) * DMODEL + k0 + tx] = f2bf(t[tx][ty + i * 8]);
}

// ---------------- GEMM: BK=64, T2 swizzle, T1 XCD swizzle, T5, explicit double-buffer ----
// 128x128 tile, 4 waves. LDS 64KB: As/Bs[2][128][64] u16, 128B rows, 16B-slot swizzle
// key row&7 (pre-swizzled global source -> linear LDS dest; reads XOR same key -> <=2-way).
// Single-barrier pipeline: stage(j+1 -> buf^1) issued BEFORE compute(j, buf); the one
// __syncthreads per iter drains vmcnt (j+1 landed) and WAR-protects via prior barrier.
__device__ __forceinline__ void storeC(u16* p, float v) { *p = f2bf(v); }
__device__ __forceinline__ void storeC(float* p, float v) { *p = v; }

template <typename OutT>
__global__ __launch_bounds__(256) void gemm_bt(const u16* __restrict__ A, const u16* __restrict__ Bt,
                                               OutT* __restrict__ C, int M, int N, int K) {
  __shared__ __align__(16) u16 As[2][128 * 64];
  __shared__ __align__(16) u16 Bs[2][128 * 64];
  int nwg = gridDim.x, q8 = nwg >> 3, bid = blockIdx.x;
  int nid = (bid & 7) * q8 + (bid >> 3);
  int mt = M >> 7;
  int m0 = (nid % mt) * 128, n0 = (nid / mt) * 128;
  int tid = threadIdx.x, wave = tid >> 6, lane = tid & 63;
  int wm = (wave >> 1) * 64, wn = (wave & 1) * 64;
  f32x4 acc[4][4] = {};
  int fr = lane & 15, fq = lane >> 4;

  // staging: issue i covers rows i*32..i*32+31; thread row = i*32 + (tid>>3),
  // source 16B-slot = (tid&7) ^ ((tid>>3)&7); LDS dest wave-uniform + lane*16B.
  int srow_ = tid >> 3;                      // 0..31
  int scol = ((tid & 7) ^ (srow_ & 7)) * 8;  // u16 col in row (pre-swizzled)
  const u16* aSrc = A + (size_t)(m0 + srow_) * K + scol;
  const u16* bSrc = Bt + (size_t)(n0 + srow_) * K + scol;
  size_t rstride = (size_t)32 * K;
  int dofs = wave * 512;  // u16; + i*2048 per issue

  int akey = (fr & 7);

  auto stage = [&](int buf, int kb) {
#pragma unroll
    for (int i = 0; i < 4; ++i) {
      stage16(aSrc + i * rstride + kb, &As[buf][0] + i * 2048 + dofs);
      stage16(bSrc + i * rstride + kb, &Bs[buf][0] + i * 2048 + dofs);
    }
  };

  int NT = K >> 6;
  stage(0, 0);
  __syncthreads();
  for (int j = 0; j < NT; ++j) {
    int cur = j & 1;
    if (j + 1 < NT) stage(cur ^ 1, (j + 1) << 6);  // in flight through compute
    const char* Ab = (const char*)&As[cur][0];
    const char* Bb = (const char*)&Bs[cur][0];
#pragma unroll
    for (int ks = 0; ks < 2; ++ks) {
      bf16x8 af[4], bfv[4];
      int slot = (ks * 4 + fq) ^ akey;
#pragma unroll
      for (int i = 0; i < 4; ++i)
        af[i] = *(const bf16x8*)(Ab + (wm + i * 16 + fr) * 128 + slot * 16);
#pragma unroll
      for (int j2 = 0; j2 < 4; ++j2)
        bfv[j2] = *(const bf16x8*)(Bb + (wn + j2 * 16 + fr) * 128 + slot * 16);
      __builtin_amdgcn_s_setprio(1);
#pragma unroll
      for (int i = 0; i < 4; ++i)
#pragma unroll
        for (int j2 = 0; j2 < 4; ++j2)
          acc[i][j2] = mfma16(af[i], bfv[j2], acc[i][j2]);
      __builtin_amdgcn_s_setprio(0);
    }
    __syncthreads();  // drains stage(j+1) vmcnt; all waves done reading buf[cur]
  }
#pragma unroll
  for (int i = 0; i < 4; ++i)
#pragma unroll
    for (int j = 0; j < 4; ++j)
#pragma unroll
      for (int r = 0; r < 4; ++r) {
        int row = m0 + wm + i * 16 + fq * 4 + r;
        int col = n0 + wn + j * 16 + fr;
        storeC(&C[(size_t)row * N + col], acc[i][j][r]);
      }
}

// ---------------- RMSNorm + RoPE (Q pre-scaled by SM_SCALE) ----------------
__global__ __launch_bounds__(256) void normrope(u16* __restrict__ QKV,
                                                const float* __restrict__ qw,
                                                const float* __restrict__ kw) {
  int wq = threadIdx.x >> 6, lane = threadIdx.x & 63;
  int gid = blockIdx.x * 4 + wq;
  int token = gid / 40, head = gid % 40;
  int pos = token & (SEQ - 1);
  const float* wrow;
  int col;
  float sc;
  if (head < NH) { wrow = qw; col = head * HD; sc = SM_SCALE; }
  else           { wrow = kw; col = DMODEL + (head - NH) * HD; sc = 1.0f; }
  u16* row = QKV + (size_t)token * QKVN + col;
  ushort2 xv = *(const ushort2*)(row + 2 * lane);
  float x1 = bf2f(xv.x), x2 = bf2f(xv.y);
  float ssq = x1 * x1 + x2 * x2;
#pragma unroll
  for (int o = 32; o; o >>= 1) ssq += __shfl_xor(ssq, o, 64);
  float rms = rsqrtf(ssq * (1.0f / HD) + RMS_EPS);
  float y1 = x1 * rms * wrow[2 * lane] * sc;
  float y2 = x2 * rms * wrow[2 * lane + 1] * sc;
  float freq = exp2f((float)lane * -0.20762050593046014f);
  float ang = (float)pos * freq;
  float s, c;
  sincosf(ang, &s, &c);
  ushort2 ov;
  ov.x = f2bf(y1 * c - y2 * s);
  ov.y = f2bf(y1 * s + y2 * c);
  *(ushort2*)(row + 2 * lane) = ov;
}

// ---------------- 8-wave 32x32 swapped-QK^T flash attention (r10, proven) ----------------
__global__ __launch_bounds__(512, 2) void attn(const u16* __restrict__ QKV, u16* __restrict__ O) {
  // XCD swizzle: grid 256 = 8 * 32
  int bid0 = blockIdx.x;
  int bid = (bid0 & 7) * 32 + (bid0 >> 3);
  int pairi = bid & 3, h = (bid >> 2) & 31, b = bid >> 7;
  int tid = threadIdx.x, wave = tid >> 6, lane = tid & 63;
  int qn = lane & 31, hi = lane >> 5;
  int hi4 = hi * 4, hi16 = hi * 16;
  int kvh = h >> 2;

  __shared__ __align__(16) u16 Ks[2][64 * 128];
  __shared__ __align__(16) u16 Vs[2][128 * 64];

  size_t tokb = (size_t)b * SEQ;
  const u16* Kg = QKV + tokb * QKVN + DMODEL + kvh * HD;
  const u16* Vg = Kg + NKV * HD;
  int srow = tid >> 4, sl = tid & 15;  // srow 0..31

  int kk0 = (qn & 7) << 4;
  int d0 = qn, d1 = 32 + qn, d2 = 64 + qn, d3 = 96 + qn;
  int vk0 = ((d0 ^ (d0 >> 3)) & 7) << 4;
  int vk1 = ((d1 ^ (d1 >> 3)) & 7) << 4;
  int vk2 = ((d2 ^ (d2 >> 3)) & 7) << 4;
  int vk3 = ((d3 ^ (d3 >> 3)) & 7) << 4;

  int4 vreg[2];
  auto loadV = [&](int kv0) {
#pragma unroll
    for (int i = 0; i < 2; ++i)
      vreg[i] = *(const int4*)(Vg + (size_t)(kv0 + i * 32 + srow) * QKVN + sl * 8);
  };
  auto stageK = [&](int buf, int kv0) {
#pragma unroll
    for (int i = 0; i < 2; ++i) {
      int row = i * 32 + srow;
      __builtin_amdgcn_global_load_lds(
          (const AS1 u32*)(Kg + (size_t)(kv0 + row) * QKVN + ((sl ^ (row & 7)) * 8)),
          (AS3 u32*)(&Ks[buf][0] + (i * 32 + wave * 4) * 128), 16, 0, 0);
    }
  };
  auto packV = [&](int buf) {
#pragma unroll
    for (int i = 0; i < 2; ++i) {
      int row = i * 32 + srow;
      int4 dvi = vreg[i];
      int4 dpi;
      dpi.x = __shfl_xor(dvi.x, 16, 64);
      dpi.y = __shfl_xor(dvi.y, 16, 64);
      dpi.z = __shfl_xor(dvi.z, 16, 64);
      dpi.w = __shfl_xor(dvi.w, 16, 64);
      if (((tid >> 4) & 1) == 0) {
        const u16* own = (const u16*)&dvi;
        const u16* par = (const u16*)&dpi;
#pragma unroll
        for (int j = 0; j < 8; ++j) {
          u32 wv = (u32)own[j] | ((u32)par[j] << 16);
          int d = sl * 8 + j;
          int vk = ((d ^ (d >> 3)) & 7) << 4;
          *(u32*)((char*)&Vs[buf][0] + d * 128 + ((2 * row) ^ vk)) = wv;
        }
      }
    }
  };

  for (int pass = 0; pass < 2; ++pass) {
    int chunk = pass ? (7 - pairi) : pairi;
    int chb = chunk * 256;
    int nt = (chunk + 1) * 4;
    int q0w = chb + wave * 32;
    int qabs = q0w + qn;
    int lim = chunk * 4 + (wave >> 1);
    int diag = q0w & ~63;

    bf16x8 qf[8];
    {
      const u16* qp = QKV + (tokb + q0w + qn) * QKVN + h * HD;
#pragma unroll
      for (int d = 0; d < 8; ++d) qf[d] = *(const bf16x8*)(qp + d * 16 + hi * 8);
    }

    f32x16 o0 = {}, o1 = {}, o2 = {}, o3 = {};
    float mrow = NEG_INF, lsum = 0.f;

    auto tile = [&](int kv0, const u16* Kl, const u16* Vl) {
      f32x16 p0v = {}, p1v = {};
      {
        const char* kb0 = (const char*)Kl + qn * 256;
        const char* kb1 = (const char*)Kl + (32 + qn) * 256;
        __builtin_amdgcn_s_setprio(1);
#pragma unroll
        for (int d = 0; d < 8; ++d) {
          bf16x8 k0 = *(const bf16x8*)(kb0 + ((d * 32 + hi16) ^ kk0));
          bf16x8 k1 = *(const bf16x8*)(kb1 + ((d * 32 + hi16) ^ kk0));
          p0v = mfma32(k0, qf[d], p0v);
          p1v = mfma32(k1, qf[d], p1v);
        }
        __builtin_amdgcn_s_setprio(0);
      }
      if (kv0 == diag) {
#pragma unroll
        for (int r = 0; r < 16; ++r) {
          int kva = kv0 + (r & 3) + 8 * (r >> 2) + hi4;
          if (kva > qabs) p0v[r] = NEG_INF;
          if (kva + 32 > qabs) p1v[r] = NEG_INF;
        }
      }
      float tmax = NEG_INF;
#pragma unroll
      for (int r = 0; r < 16; ++r) tmax = fmaxf(tmax, fmaxf(p0v[r], p1v[r]));
      tmax = fmaxf(tmax, __shfl_xor(tmax, 32, 64));
      if (!__all(tmax <= mrow + 8.0f)) {
        float nm = fmaxf(mrow, tmax);
        float corr = __expf(mrow - nm);
        mrow = nm;
        lsum *= corr;
#pragma unroll
        for (int r = 0; r < 16; ++r) {
          int srcl = (r & 3) + 8 * (r >> 2) + hi4;
          float cr = __shfl(corr, srcl, 64);
          o0[r] *= cr; o1[r] *= cr; o2[r] *= cr; o3[r] *= cr;
        }
      }
      float rs = 0.f;
#pragma unroll
      for (int r = 0; r < 16; ++r) {
        p0v[r] = __expf(p0v[r] - mrow);
        p1v[r] = __expf(p1v[r] - mrow);
        rs += p0v[r] + p1v[r];
      }
      rs += __shfl_xor(rs, 32, 64);
      lsum += rs;

      auto pv = [&](const f32x16& pk, int kvs) {
#pragma unroll
        for (int e = 0; e < 2; ++e) {
          u32 A = packbf(pk[e * 8 + 0], pk[e * 8 + 1]);
          u32 Bw = packbf(pk[e * 8 + 2], pk[e * 8 + 3]);
          u32 C = packbf(pk[e * 8 + 4], pk[e * 8 + 5]);
          u32 Dw = packbf(pk[e * 8 + 6], pk[e * 8 + 7]);
          u32 sA = __shfl_xor(A, 32, 64), sC = __shfl_xor(C, 32, 64);
          u32 sB = __shfl_xor(Bw, 32, 64), sD = __shfl_xor(Dw, 32, 64);
          union { u32 w[4]; bf16x8 v; } fr;
          fr.w[0] = hi ? sC : A;
          fr.w[1] = hi ? sD : Bw;
          fr.w[2] = hi ? C : sA;
          fr.w[3] = hi ? Dw : sB;
          int off = (kvs * 2 + e) * 32 + hi16;
          __builtin_amdgcn_s_setprio(1);
          o0 = mfma32(fr.v, *(const bf16x8*)((const char*)Vl + d0 * 128 + (off ^ vk0)), o0);
          o1 = mfma32(fr.v, *(const bf16x8*)((const char*)Vl + d1 * 128 + (off ^ vk1)), o1);
          o2 = mfma32(fr.v, *(const bf16x8*)((const char*)Vl + d2 * 128 + (off ^ vk2)), o2);
          o3 = mfma32(fr.v, *(const bf16x8*)((const char*)Vl + d3 * 128 + (off ^ vk3)), o3);
          __builtin_amdgcn_s_setprio(0);
        }
      };
      pv(p0v, 0);
      pv(p1v, 1);
    };

    loadV(0);
    stageK(0, 0);
    packV(0);
    __syncthreads();

    for (int t = 0; t < nt; ++t) {
      int cur = t & 1, nxt = cur ^ 1;
      bool more = (t + 1) < nt;
      if (more) {
        loadV((t + 1) * 64);
        stageK(nxt, (t + 1) * 64);
      }
      if (t <= lim) tile(t * 64, &Ks[cur][0], &Vs[cur][0]);
      if (more) packV(nxt);
      __syncthreads();
    }

#pragma unroll
    for (int r = 0; r < 16; ++r) {
      int ql = (r & 3) + 8 * (r >> 2) + hi4;
      float ls = __shfl(lsum, ql, 64);
      float inv = 1.0f / ls;
      size_t base = (tokb + chb + wave * 32 + ql) * (size_t)DMODEL + h * HD + qn;
      O[base] = f2bf(o0[r] * inv);
      O[base + 32] = f2bf(o1[r] * inv);
      O[base + 64] = f2bf(o2[r] * inv);
      O[base + 96] = f2bf(o3[r] * inv);
    }
  }
}

extern "C" void kernel_launch(void* const* d_in, const int* in_sizes, int n_in,
                              void* d_out, int out_size, void* d_ws, size_t ws_size,
                              hipStream_t stream) {
  const float* x  = (const float*)d_in[0];
  const float* Wq = (const float*)d_in[1];
  const float* Wk = (const float*)d_in[2];
  const float* Wv = (const float*)d_in[3];
  const float* Wo = (const float*)d_in[4];
  const float* qw = (const float*)d_in[5];
  const float* kw = (const float*)d_in[6];
  float* out = (float*)d_out;

  // Workspace (128 MiB):
  //   [0,   32M)  xb (bf16 x)  -- dead after GEMM1 -> reused as Wot
  //   [32M, 64M)  AO (attn out; region dead after GEMM1)
  //   [32M, 80M)  Wqkvt        -- dead after GEMM1
  //   [80M, 128M) QKVb
  char* ws = (char*)d_ws;
  u16* xb    = (u16*)(ws);
  u16* Wqkvt = (u16*)(ws + 33554432);
  u16* QKVb  = (u16*)(ws + 83886080);
  u16* Wot   = xb;
  u16* AO    = Wqkvt;

  cvt_f32_bf16<<<2048, 256, 0, stream>>>(x, xb, (2 * SEQ * DMODEL) / 4);
  dim3 tb(32, 8);
  tconv<<<dim3(DMODEL / 32, DMODEL / 32), tb, 0, stream>>>(Wq, Wqkvt, DMODEL, 0);
  tconv<<<dim3((NKV * HD) / 32, DMODEL / 32), tb, 0, stream>>>(Wk, Wqkvt, NKV * HD, DMODEL);
  tconv<<<dim3((NKV * HD) / 32, DMODEL / 32), tb, 0, stream>>>(Wv, Wqkvt, NKV * HD, DMODEL + NKV * HD);

  gemm_bt<u16><<<(4096 / 128) * (QKVN / 128), 256, 0, stream>>>(xb, Wqkvt, QKVb, 4096, QKVN, DMODEL);
  normrope<<<(4096 * 40) / 4, 256, 0, stream>>>(QKVb, qw, kw);

  tconv<<<dim3(DMODEL / 32, DMODEL / 32), tb, 0, stream>>>(Wo, Wot, DMODEL, 0);
  attn<<<256, 512, 0, stream>>>(QKVb, AO);
  gemm_bt<float><<<(4096 / 128) * (DMODEL / 128), 256, 0, stream>>>(AO, Wot, out, 4096, DMODEL, DMODEL);
}

// Round 13
// 573.807 us; speedup vs baseline: 1.2337x; 1.0259x over previous
//
#include <hip/hip_runtime.h>

typedef unsigned short u16;
typedef unsigned int u32;
typedef __attribute__((ext_vector_type(8))) short bf16x8;
typedef __attribute__((ext_vector_type(4))) float f32x4;
typedef __attribute__((ext_vector_type(16))) float f32x16;

#define NH 32
#define NKV 8
#define HD 128
#define SEQ 2048
#define DMODEL 4096
#define QKVN 6144
#define RMS_EPS 1e-6f
#define SM_SCALE 0.08838834764831845f
#define NEG_INF -1e30f

#define AS1 __attribute__((address_space(1)))
#define AS3 __attribute__((address_space(3)))

__device__ __forceinline__ u16 f2bf(float f) {
  unsigned int u = __float_as_uint(f);
  u += 0x7FFFu + ((u >> 16) & 1u);
  return (u16)(u >> 16);
}
__device__ __forceinline__ float bf2f(u16 b) {
  return __uint_as_float(((unsigned int)b) << 16);
}
__device__ __forceinline__ u32 packbf(float lo, float hi) {
  u32 a = __float_as_uint(lo) + 0x8000u;
  u32 b = __float_as_uint(hi) + 0x8000u;
  return __builtin_amdgcn_perm(b, a, 0x07060302u);
}

__device__ __forceinline__ f32x4 mfma16(bf16x8 a, bf16x8 b, f32x4 c) {
  return __builtin_amdgcn_mfma_f32_16x16x32_bf16(a, b, c, 0, 0, 0);
}
__device__ __forceinline__ f32x16 mfma32(bf16x8 a, bf16x8 b, f32x16 c) {
  return __builtin_amdgcn_mfma_f32_32x32x16_bf16(a, b, c, 0, 0, 0);
}

__device__ __forceinline__ void stage16(const u16* g, u16* l) {
  __builtin_amdgcn_global_load_lds((const AS1 u32*)g, (AS3 u32*)l, 16, 0, 0);
}

// ---------------- convert x: f32 -> bf16 ----------------
__global__ __launch_bounds__(256) void cvt_f32_bf16(const float* __restrict__ in,
                                                    u16* __restrict__ out, int n4) {
  int stride = gridDim.x * blockDim.x;
  for (int i = blockIdx.x * blockDim.x + threadIdx.x; i < n4; i += stride) {
    float4 v = ((const float4*)in)[i];
    ushort4 o;
    o.x = f2bf(v.x); o.y = f2bf(v.y); o.z = f2bf(v.z); o.w = f2bf(v.w);
    ((ushort4*)out)[i] = o;
  }
}

// ---------------- transpose-convert W[K=4096][N] f32 -> Wt[rowoff+N][4096] bf16 ----------------
__global__ __launch_bounds__(256) void tconv(const float* __restrict__ W, u16* __restrict__ Wt,
                                             int N, int rowoff) {
  __shared__ float t[32][33];
  int n0 = blockIdx.x * 32, k0 = blockIdx.y * 32;
  int tx = threadIdx.x, ty = threadIdx.y;  // (32,8)
#pragma unroll
  for (int i = 0; i < 4; ++i)
    t[ty + i * 8][tx] = W[(size_t)(k0 + ty + i * 8) * N + n0 + tx];
  __syncthreads();
#pragma unroll
  for (int i = 0; i < 4; ++i)
    Wt[(size_t)(rowoff + n0 + ty + i * 8) * DMODEL + k0 + tx] = f2bf(t[tx][ty + i * 8]);
}

__device__ __forceinline__ void storeC(u16* p, float v) { *p = f2bf(v); }
__device__ __forceinline__ void storeC(float* p, float v) { *p = v; }

// ---------------- GEMM A (r11): BK=64, single LDS buffer, 2-barrier loop ----------------
// Best for gemm1 (1536 blocks, ~2.5 blocks/CU). 1006 TF measured, conflicts 0.
template <typename OutT>
__global__ __launch_bounds__(256) void gemm_sb(const u16* __restrict__ A, const u16* __restrict__ Bt,
                                               OutT* __restrict__ C, int M, int N, int K) {
  __shared__ __align__(16) u16 As[128 * 64];
  __shared__ __align__(16) u16 Bs[128 * 64];
  int nwg = gridDim.x, q8 = nwg >> 3, bid = blockIdx.x;
  int nid = (bid & 7) * q8 + (bid >> 3);
  int mt = M >> 7;
  int m0 = (nid % mt) * 128, n0 = (nid / mt) * 128;
  int tid = threadIdx.x, wave = tid >> 6, lane = tid & 63;
  int wm = (wave >> 1) * 64, wn = (wave & 1) * 64;
  f32x4 acc[4][4] = {};
  int fr = lane & 15, fq = lane >> 4;

  int srow_ = tid >> 3;                      // 0..31
  int scol = ((tid & 7) ^ (srow_ & 7)) * 8;  // pre-swizzled source slot
  const u16* aSrc = A + (size_t)(m0 + srow_) * K + scol;
  const u16* bSrc = Bt + (size_t)(n0 + srow_) * K + scol;
  size_t rstride = (size_t)32 * K;
  int dofs = wave * 512;
  int akey = (fr & 7);

  for (int kb = 0; kb < K; kb += 64) {
    __syncthreads();
#pragma unroll
    for (int i = 0; i < 4; ++i) {
      stage16(aSrc + i * rstride + kb, As + i * 2048 + dofs);
      stage16(bSrc + i * rstride + kb, Bs + i * 2048 + dofs);
    }
    __syncthreads();
#pragma unroll
    for (int ks = 0; ks < 2; ++ks) {
      bf16x8 af[4], bfv[4];
      int slot = (ks * 4 + fq) ^ akey;
#pragma unroll
      for (int i = 0; i < 4; ++i)
        af[i] = *(const bf16x8*)((const char*)As + (wm + i * 16 + fr) * 128 + slot * 16);
#pragma unroll
      for (int j = 0; j < 4; ++j)
        bfv[j] = *(const bf16x8*)((const char*)Bs + (wn + j * 16 + fr) * 128 + slot * 16);
      __builtin_amdgcn_s_setprio(1);
#pragma unroll
      for (int i = 0; i < 4; ++i)
#pragma unroll
        for (int j = 0; j < 4; ++j)
          acc[i][j] = mfma16(af[i], bfv[j], acc[i][j]);
      __builtin_amdgcn_s_setprio(0);
    }
  }
#pragma unroll
  for (int i = 0; i < 4; ++i)
#pragma unroll
    for (int j = 0; j < 4; ++j)
#pragma unroll
      for (int r = 0; r < 4; ++r) {
        int row = m0 + wm + i * 16 + fq * 4 + r;
        int col = n0 + wn + j * 16 + fr;
        storeC(&C[(size_t)row * N + col], acc[i][j][r]);
      }
}

// ---------------- GEMM B (r12): BK=64, explicit double-buffer, 1-barrier loop ----------------
// Best for gemm2 (1024 blocks -> exactly 2 generations at 2 blocks/CU). ~130 us measured.
template <typename OutT>
__global__ __launch_bounds__(256) void gemm_db(const u16* __restrict__ A, const u16* __restrict__ Bt,
                                               OutT* __restrict__ C, int M, int N, int K) {
  __shared__ __align__(16) u16 As[2][128 * 64];
  __shared__ __align__(16) u16 Bs[2][128 * 64];
  int nwg = gridDim.x, q8 = nwg >> 3, bid = blockIdx.x;
  int nid = (bid & 7) * q8 + (bid >> 3);
  int mt = M >> 7;
  int m0 = (nid % mt) * 128, n0 = (nid / mt) * 128;
  int tid = threadIdx.x, wave = tid >> 6, lane = tid & 63;
  int wm = (wave >> 1) * 64, wn = (wave & 1) * 64;
  f32x4 acc[4][4] = {};
  int fr = lane & 15, fq = lane >> 4;

  int srow_ = tid >> 3;
  int scol = ((tid & 7) ^ (srow_ & 7)) * 8;
  const u16* aSrc = A + (size_t)(m0 + srow_) * K + scol;
  const u16* bSrc = Bt + (size_t)(n0 + srow_) * K + scol;
  size_t rstride = (size_t)32 * K;
  int dofs = wave * 512;
  int akey = (fr & 7);

  auto stage = [&](int buf, int kb) {
#pragma unroll
    for (int i = 0; i < 4; ++i) {
      stage16(aSrc + i * rstride + kb, &As[buf][0] + i * 2048 + dofs);
      stage16(bSrc + i * rstride + kb, &Bs[buf][0] + i * 2048 + dofs);
    }
  };

  int NT = K >> 6;
  stage(0, 0);
  __syncthreads();
  for (int j = 0; j < NT; ++j) {
    int cur = j & 1;
    if (j + 1 < NT) stage(cur ^ 1, (j + 1) << 6);
    const char* Ab = (const char*)&As[cur][0];
    const char* Bb = (const char*)&Bs[cur][0];
#pragma unroll
    for (int ks = 0; ks < 2; ++ks) {
      bf16x8 af[4], bfv[4];
      int slot = (ks * 4 + fq) ^ akey;
#pragma unroll
      for (int i = 0; i < 4; ++i)
        af[i] = *(const bf16x8*)(Ab + (wm + i * 16 + fr) * 128 + slot * 16);
#pragma unroll
      for (int j2 = 0; j2 < 4; ++j2)
        bfv[j2] = *(const bf16x8*)(Bb + (wn + j2 * 16 + fr) * 128 + slot * 16);
      __builtin_amdgcn_s_setprio(1);
#pragma unroll
      for (int i = 0; i < 4; ++i)
#pragma unroll
        for (int j2 = 0; j2 < 4; ++j2)
          acc[i][j2] = mfma16(af[i], bfv[j2], acc[i][j2]);
      __builtin_amdgcn_s_setprio(0);
    }
    __syncthreads();
  }
#pragma unroll
  for (int i = 0; i < 4; ++i)
#pragma unroll
    for (int j = 0; j < 4; ++j)
#pragma unroll
      for (int r = 0; r < 4; ++r) {
        int row = m0 + wm + i * 16 + fq * 4 + r;
        int col = n0 + wn + j * 16 + fr;
        storeC(&C[(size_t)row * N + col], acc[i][j][r]);
      }
}

// ---------------- RMSNorm + RoPE (Q pre-scaled by SM_SCALE) ----------------
__global__ __launch_bounds__(256) void normrope(u16* __restrict__ QKV,
                                                const float* __restrict__ qw,
                                                const float* __restrict__ kw) {
  int wq = threadIdx.x >> 6, lane = threadIdx.x & 63;
  int gid = blockIdx.x * 4 + wq;
  int token = gid / 40, head = gid % 40;
  int pos = token & (SEQ - 1);
  const float* wrow;
  int col;
  float sc;
  if (head < NH) { wrow = qw; col = head * HD; sc = SM_SCALE; }
  else           { wrow = kw; col = DMODEL + (head - NH) * HD; sc = 1.0f; }
  u16* row = QKV + (size_t)token * QKVN + col;
  ushort2 xv = *(const ushort2*)(row + 2 * lane);
  float x1 = bf2f(xv.x), x2 = bf2f(xv.y);
  float ssq = x1 * x1 + x2 * x2;
#pragma unroll
  for (int o = 32; o; o >>= 1) ssq += __shfl_xor(ssq, o, 64);
  float rms = rsqrtf(ssq * (1.0f / HD) + RMS_EPS);
  float y1 = x1 * rms * wrow[2 * lane] * sc;
  float y2 = x2 * rms * wrow[2 * lane + 1] * sc;
  float freq = exp2f((float)lane * -0.20762050593046014f);
  float ang = (float)pos * freq;
  float s, c;
  sincosf(ang, &s, &c);
  ushort2 ov;
  ov.x = f2bf(y1 * c - y2 * s);
  ov.y = f2bf(y1 * s + y2 * c);
  *(ushort2*)(row + 2 * lane) = ov;
}

// ---------------- 8-wave 32x32 swapped-QK^T flash attention (r10, proven) ----------------
__global__ __launch_bounds__(512, 2) void attn(const u16* __restrict__ QKV, u16* __restrict__ O) {
  // XCD swizzle: grid 256 = 8 * 32
  int bid0 = blockIdx.x;
  int bid = (bid0 & 7) * 32 + (bid0 >> 3);
  int pairi = bid & 3, h = (bid >> 2) & 31, b = bid >> 7;
  int tid = threadIdx.x, wave = tid >> 6, lane = tid & 63;
  int qn = lane & 31, hi = lane >> 5;
  int hi4 = hi * 4, hi16 = hi * 16;
  int kvh = h >> 2;

  __shared__ __align__(16) u16 Ks[2][64 * 128];
  __shared__ __align__(16) u16 Vs[2][128 * 64];

  size_t tokb = (size_t)b * SEQ;
  const u16* Kg = QKV + tokb * QKVN + DMODEL + kvh * HD;
  const u16* Vg = Kg + NKV * HD;
  int srow = tid >> 4, sl = tid & 15;  // srow 0..31

  int kk0 = (qn & 7) << 4;
  int d0 = qn, d1 = 32 + qn, d2 = 64 + qn, d3 = 96 + qn;
  int vk0 = ((d0 ^ (d0 >> 3)) & 7) << 4;
  int vk1 = ((d1 ^ (d1 >> 3)) & 7) << 4;
  int vk2 = ((d2 ^ (d2 >> 3)) & 7) << 4;
  int vk3 = ((d3 ^ (d3 >> 3)) & 7) << 4;

  int4 vreg[2];
  auto loadV = [&](int kv0) {
#pragma unroll
    for (int i = 0; i < 2; ++i)
      vreg[i] = *(const int4*)(Vg + (size_t)(kv0 + i * 32 + srow) * QKVN + sl * 8);
  };
  auto stageK = [&](int buf, int kv0) {
#pragma unroll
    for (int i = 0; i < 2; ++i) {
      int row = i * 32 + srow;
      __builtin_amdgcn_global_load_lds(
          (const AS1 u32*)(Kg + (size_t)(kv0 + row) * QKVN + ((sl ^ (row & 7)) * 8)),
          (AS3 u32*)(&Ks[buf][0] + (i * 32 + wave * 4) * 128), 16, 0, 0);
    }
  };
  auto packV = [&](int buf) {
#pragma unroll
    for (int i = 0; i < 2; ++i) {
      int row = i * 32 + srow;
      int4 dvi = vreg[i];
      int4 dpi;
      dpi.x = __shfl_xor(dvi.x, 16, 64);
      dpi.y = __shfl_xor(dvi.y, 16, 64);
      dpi.z = __shfl_xor(dvi.z, 16, 64);
      dpi.w = __shfl_xor(dvi.w, 16, 64);
      if (((tid >> 4) & 1) == 0) {
        const u16* own = (const u16*)&dvi;
        const u16* par = (const u16*)&dpi;
#pragma unroll
        for (int j = 0; j < 8; ++j) {
          u32 wv = (u32)own[j] | ((u32)par[j] << 16);
          int d = sl * 8 + j;
          int vk = ((d ^ (d >> 3)) & 7) << 4;
          *(u32*)((char*)&Vs[buf][0] + d * 128 + ((2 * row) ^ vk)) = wv;
        }
      }
    }
  };

  for (int pass = 0; pass < 2; ++pass) {
    int chunk = pass ? (7 - pairi) : pairi;
    int chb = chunk * 256;
    int nt = (chunk + 1) * 4;
    int q0w = chb + wave * 32;
    int qabs = q0w + qn;
    int lim = chunk * 4 + (wave >> 1);
    int diag = q0w & ~63;

    bf16x8 qf[8];
    {
      const u16* qp = QKV + (tokb + q0w + qn) * QKVN + h * HD;
#pragma unroll
      for (int d = 0; d < 8; ++d) qf[d] = *(const bf16x8*)(qp + d * 16 + hi * 8);
    }

    f32x16 o0 = {}, o1 = {}, o2 = {}, o3 = {};
    float mrow = NEG_INF, lsum = 0.f;

    auto tile = [&](int kv0, const u16* Kl, const u16* Vl) {
      f32x16 p0v = {}, p1v = {};
      {
        const char* kb0 = (const char*)Kl + qn * 256;
        const char* kb1 = (const char*)Kl + (32 + qn) * 256;
        __builtin_amdgcn_s_setprio(1);
#pragma unroll
        for (int d = 0; d < 8; ++d) {
          bf16x8 k0 = *(const bf16x8*)(kb0 + ((d * 32 + hi16) ^ kk0));
          bf16x8 k1 = *(const bf16x8*)(kb1 + ((d * 32 + hi16) ^ kk0));
          p0v = mfma32(k0, qf[d], p0v);
          p1v = mfma32(k1, qf[d], p1v);
        }
        __builtin_amdgcn_s_setprio(0);
      }
      if (kv0 == diag) {
#pragma unroll
        for (int r = 0; r < 16; ++r) {
          int kva = kv0 + (r & 3) + 8 * (r >> 2) + hi4;
          if (kva > qabs) p0v[r] = NEG_INF;
          if (kva + 32 > qabs) p1v[r] = NEG_INF;
        }
      }
      float tmax = NEG_INF;
#pragma unroll
      for (int r = 0; r < 16; ++r) tmax = fmaxf(tmax, fmaxf(p0v[r], p1v[r]));
      tmax = fmaxf(tmax, __shfl_xor(tmax, 32, 64));
      if (!__all(tmax <= mrow + 8.0f)) {
        float nm = fmaxf(mrow, tmax);
        float corr = __expf(mrow - nm);
        mrow = nm;
        lsum *= corr;
#pragma unroll
        for (int r = 0; r < 16; ++r) {
          int srcl = (r & 3) + 8 * (r >> 2) + hi4;
          float cr = __shfl(corr, srcl, 64);
          o0[r] *= cr; o1[r] *= cr; o2[r] *= cr; o3[r] *= cr;
        }
      }
      float rs = 0.f;
#pragma unroll
      for (int r = 0; r < 16; ++r) {
        p0v[r] = __expf(p0v[r] - mrow);
        p1v[r] = __expf(p1v[r] - mrow);
        rs += p0v[r] + p1v[r];
      }
      rs += __shfl_xor(rs, 32, 64);
      lsum += rs;

      auto pv = [&](const f32x16& pk, int kvs) {
#pragma unroll
        for (int e = 0; e < 2; ++e) {
          u32 A = packbf(pk[e * 8 + 0], pk[e * 8 + 1]);
          u32 Bw = packbf(pk[e * 8 + 2], pk[e * 8 + 3]);
          u32 C = packbf(pk[e * 8 + 4], pk[e * 8 + 5]);
          u32 Dw = packbf(pk[e * 8 + 6], pk[e * 8 + 7]);
          u32 sA = __shfl_xor(A, 32, 64), sC = __shfl_xor(C, 32, 64);
          u32 sB = __shfl_xor(Bw, 32, 64), sD = __shfl_xor(Dw, 32, 64);
          union { u32 w[4]; bf16x8 v; } fr;
          fr.w[0] = hi ? sC : A;
          fr.w[1] = hi ? sD : Bw;
          fr.w[2] = hi ? C : sA;
          fr.w[3] = hi ? Dw : sB;
          int off = (kvs * 2 + e) * 32 + hi16;
          __builtin_amdgcn_s_setprio(1);
          o0 = mfma32(fr.v, *(const bf16x8*)((const char*)Vl + d0 * 128 + (off ^ vk0)), o0);
          o1 = mfma32(fr.v, *(const bf16x8*)((const char*)Vl + d1 * 128 + (off ^ vk1)), o1);
          o2 = mfma32(fr.v, *(const bf16x8*)((const char*)Vl + d2 * 128 + (off ^ vk2)), o2);
          o3 = mfma32(fr.v, *(const bf16x8*)((const char*)Vl + d3 * 128 + (off ^ vk3)), o3);
          __builtin_amdgcn_s_setprio(0);
        }
      };
      pv(p0v, 0);
      pv(p1v, 1);
    };

    loadV(0);
    stageK(0, 0);
    packV(0);
    __syncthreads();

    for (int t = 0; t < nt; ++t) {
      int cur = t & 1, nxt = cur ^ 1;
      bool more = (t + 1) < nt;
      if (more) {
        loadV((t + 1) * 64);
        stageK(nxt, (t + 1) * 64);
      }
      if (t <= lim) tile(t * 64, &Ks[cur][0], &Vs[cur][0]);
      if (more) packV(nxt);
      __syncthreads();
    }

#pragma unroll
    for (int r = 0; r < 16; ++r) {
      int ql = (r & 3) + 8 * (r >> 2) + hi4;
      float ls = __shfl(lsum, ql, 64);
      float inv = 1.0f / ls;
      size_t base = (tokb + chb + wave * 32 + ql) * (size_t)DMODEL + h * HD + qn;
      O[base] = f2bf(o0[r] * inv);
      O[base + 32] = f2bf(o1[r] * inv);
      O[base + 64] = f2bf(o2[r] * inv);
      O[base + 96] = f2bf(o3[r] * inv);
    }
  }
}

extern "C" void kernel_launch(void* const* d_in, const int* in_sizes, int n_in,
                              void* d_out, int out_size, void* d_ws, size_t ws_size,
                              hipStream_t stream) {
  const float* x  = (const float*)d_in[0];
  const float* Wq = (const float*)d_in[1];
  const float* Wk = (const float*)d_in[2];
  const float* Wv = (const float*)d_in[3];
  const float* Wo = (const float*)d_in[4];
  const float* qw = (const float*)d_in[5];
  const float* kw = (const float*)d_in[6];
  float* out = (float*)d_out;

  // Workspace (128 MiB):
  //   [0,   32M)  xb (bf16 x)  -- dead after GEMM1 -> reused as Wot
  //   [32M, 64M)  AO (attn out; region dead after GEMM1)
  //   [32M, 80M)  Wqkvt        -- dead after GEMM1
  //   [80M, 128M) QKVb
  char* ws = (char*)d_ws;
  u16* xb    = (u16*)(ws);
  u16* Wqkvt = (u16*)(ws + 33554432);
  u16* QKVb  = (u16*)(ws + 83886080);
  u16* Wot   = xb;
  u16* AO    = Wqkvt;

  cvt_f32_bf16<<<2048, 256, 0, stream>>>(x, xb, (2 * SEQ * DMODEL) / 4);
  dim3 tb(32, 8);
  tconv<<<dim3(DMODEL / 32, DMODEL / 32), tb, 0, stream>>>(Wq, Wqkvt, DMODEL, 0);
  tconv<<<dim3((NKV * HD) / 32, DMODEL / 32), tb, 0, stream>>>(Wk, Wqkvt, NKV * HD, DMODEL);
  tconv<<<dim3((NKV * HD) / 32, DMODEL / 32), tb, 0, stream>>>(Wv, Wqkvt, NKV * HD, DMODEL + NKV * HD);

  // gemm1: 1536 blocks -> single-buffer template (higher occupancy, ~2.4 gens)
  gemm_sb<u16><<<(4096 / 128) * (QKVN / 128), 256, 0, stream>>>(xb, Wqkvt, QKVb, 4096, QKVN, DMODEL);
  normrope<<<(4096 * 40) / 4, 256, 0, stream>>>(QKVb, qw, kw);

  tconv<<<dim3(DMODEL / 32, DMODEL / 32), tb, 0, stream>>>(Wo, Wot, DMODEL, 0);
  attn<<<256, 512, 0, stream>>>(QKVb, AO);
  // gemm2: 1024 blocks -> double-buffer template (2 blocks/CU, exactly 2 generations)
  gemm_db<float><<<(4096 / 128) * (DMODEL / 128), 256, 0, stream>>>(AO, Wot, out, 4096, DMODEL, DMODEL);
}

// Round 14
// 564.944 us; speedup vs baseline: 1.2530x; 1.0157x over previous
//
#include <hip/hip_runtime.h>

typedef unsigned short u16;
typedef unsigned int u32;
typedef __attribute__((ext_vector_type(8))) short bf16x8;
typedef __attribute__((ext_vector_type(4))) float f32x4;
typedef __attribute__((ext_vector_type(16))) float f32x16;

#define NH 32
#define NKV 8
#define HD 128
#define SEQ 2048
#define DMODEL 4096
#define QKVN 6144
#define RMS_EPS 1e-6f
#define SM_SCALE 0.08838834764831845f
#define NEG_INF -1e30f

#define AS1 __attribute__((address_space(1)))
#define AS3 __attribute__((address_space(3)))

__device__ __forceinline__ u16 f2bf(float f) {
  unsigned int u = __float_as_uint(f);
  u += 0x7FFFu + ((u >> 16) & 1u);
  return (u16)(u >> 16);
}
__device__ __forceinline__ float bf2f(u16 b) {
  return __uint_as_float(((unsigned int)b) << 16);
}
__device__ __forceinline__ u32 packbf(float lo, float hi) {
  u32 a = __float_as_uint(lo) + 0x8000u;
  u32 b = __float_as_uint(hi) + 0x8000u;
  return __builtin_amdgcn_perm(b, a, 0x07060302u);
}

__device__ __forceinline__ f32x4 mfma16(bf16x8 a, bf16x8 b, f32x4 c) {
  return __builtin_amdgcn_mfma_f32_16x16x32_bf16(a, b, c, 0, 0, 0);
}
__device__ __forceinline__ f32x16 mfma32(bf16x8 a, bf16x8 b, f32x16 c) {
  return __builtin_amdgcn_mfma_f32_32x32x16_bf16(a, b, c, 0, 0, 0);
}

__device__ __forceinline__ void stage16(const u16* g, u16* l) {
  __builtin_amdgcn_global_load_lds((const AS1 u32*)g, (AS3 u32*)l, 16, 0, 0);
}

// ---------------- convert x: f32 -> bf16 ----------------
__global__ __launch_bounds__(256) void cvt_f32_bf16(const float* __restrict__ in,
                                                    u16* __restrict__ out, int n4) {
  int stride = gridDim.x * blockDim.x;
  for (int i = blockIdx.x * blockDim.x + threadIdx.x; i < n4; i += stride) {
    float4 v = ((const float4*)in)[i];
    ushort4 o;
    o.x = f2bf(v.x); o.y = f2bf(v.y); o.z = f2bf(v.z); o.w = f2bf(v.w);
    ((ushort4*)out)[i] = o;
  }
}

// ---------------- transpose-convert W[K=4096][N] f32 -> Wt[rowoff+N][4096] bf16 ----------
// 64x64 tile, 256 threads. LDS [64][66] f32 (pad 66 -> 2-way-max banks both phases,
// 8B-aligned rows). Loads: 256B/wave coalesced. Stores: ushort2, 128B/wave coalesced.
__global__ __launch_bounds__(256) void tconv(const float* __restrict__ W, u16* __restrict__ Wt,
                                             int N, int rowoff) {
  __shared__ float t[64][66];
  int n0 = blockIdx.x * 64, k0 = blockIdx.y * 64;
  int tid = threadIdx.x;
  int ln = tid & 63;   // n within tile (load phase)
  int lk = tid >> 6;   // k sub-row (0..3)
#pragma unroll
  for (int i = 0; i < 16; ++i) {
    int kk = lk + i * 4;
    t[ln][kk] = W[(size_t)(k0 + kk) * N + n0 + ln];
  }
  __syncthreads();
  int kc = tid & 31;   // 32 x 2k = 64 k
  int nr = tid >> 5;   // 0..7
#pragma unroll
  for (int j = 0; j < 8; ++j) {
    int n = nr + j * 8;
    float2 f = *(const float2*)&t[n][kc * 2];
    ushort2 o;
    o.x = f2bf(f.x);
    o.y = f2bf(f.y);
    *(ushort2*)&Wt[(size_t)(rowoff + n0 + n) * DMODEL + k0 + kc * 2] = o;
  }
}

__device__ __forceinline__ void storeC(u16* p, float v) { *p = f2bf(v); }
__device__ __forceinline__ void storeC(float* p, float v) { *p = v; }

// ---------------- GEMM A (r11): BK=64, single LDS buffer, 2-barrier loop ----------------
template <typename OutT>
__global__ __launch_bounds__(256) void gemm_sb(const u16* __restrict__ A, const u16* __restrict__ Bt,
                                               OutT* __restrict__ C, int M, int N, int K) {
  __shared__ __align__(16) u16 As[128 * 64];
  __shared__ __align__(16) u16 Bs[128 * 64];
  int nwg = gridDim.x, q8 = nwg >> 3, bid = blockIdx.x;
  int nid = (bid & 7) * q8 + (bid >> 3);
  int mt = M >> 7;
  int m0 = (nid % mt) * 128, n0 = (nid / mt) * 128;
  int tid = threadIdx.x, wave = tid >> 6, lane = tid & 63;
  int wm = (wave >> 1) * 64, wn = (wave & 1) * 64;
  f32x4 acc[4][4] = {};
  int fr = lane & 15, fq = lane >> 4;

  int srow_ = tid >> 3;
  int scol = ((tid & 7) ^ (srow_ & 7)) * 8;
  const u16* aSrc = A + (size_t)(m0 + srow_) * K + scol;
  const u16* bSrc = Bt + (size_t)(n0 + srow_) * K + scol;
  size_t rstride = (size_t)32 * K;
  int dofs = wave * 512;
  int akey = (fr & 7);

  for (int kb = 0; kb < K; kb += 64) {
    __syncthreads();
#pragma unroll
    for (int i = 0; i < 4; ++i) {
      stage16(aSrc + i * rstride + kb, As + i * 2048 + dofs);
      stage16(bSrc + i * rstride + kb, Bs + i * 2048 + dofs);
    }
    __syncthreads();
#pragma unroll
    for (int ks = 0; ks < 2; ++ks) {
      bf16x8 af[4], bfv[4];
      int slot = (ks * 4 + fq) ^ akey;
#pragma unroll
      for (int i = 0; i < 4; ++i)
        af[i] = *(const bf16x8*)((const char*)As + (wm + i * 16 + fr) * 128 + slot * 16);
#pragma unroll
      for (int j = 0; j < 4; ++j)
        bfv[j] = *(const bf16x8*)((const char*)Bs + (wn + j * 16 + fr) * 128 + slot * 16);
      __builtin_amdgcn_s_setprio(1);
#pragma unroll
      for (int i = 0; i < 4; ++i)
#pragma unroll
        for (int j = 0; j < 4; ++j)
          acc[i][j] = mfma16(af[i], bfv[j], acc[i][j]);
      __builtin_amdgcn_s_setprio(0);
    }
  }
#pragma unroll
  for (int i = 0; i < 4; ++i)
#pragma unroll
    for (int j = 0; j < 4; ++j)
#pragma unroll
      for (int r = 0; r < 4; ++r) {
        int row = m0 + wm + i * 16 + fq * 4 + r;
        int col = n0 + wn + j * 16 + fr;
        storeC(&C[(size_t)row * N + col], acc[i][j][r]);
      }
}

// ---------------- GEMM B (r12): BK=64, explicit double-buffer, 1-barrier loop ----------------
template <typename OutT>
__global__ __launch_bounds__(256) void gemm_db(const u16* __restrict__ A, const u16* __restrict__ Bt,
                                               OutT* __restrict__ C, int M, int N, int K) {
  __shared__ __align__(16) u16 As[2][128 * 64];
  __shared__ __align__(16) u16 Bs[2][128 * 64];
  int nwg = gridDim.x, q8 = nwg >> 3, bid = blockIdx.x;
  int nid = (bid & 7) * q8 + (bid >> 3);
  int mt = M >> 7;
  int m0 = (nid % mt) * 128, n0 = (nid / mt) * 128;
  int tid = threadIdx.x, wave = tid >> 6, lane = tid & 63;
  int wm = (wave >> 1) * 64, wn = (wave & 1) * 64;
  f32x4 acc[4][4] = {};
  int fr = lane & 15, fq = lane >> 4;

  int srow_ = tid >> 3;
  int scol = ((tid & 7) ^ (srow_ & 7)) * 8;
  const u16* aSrc = A + (size_t)(m0 + srow_) * K + scol;
  const u16* bSrc = Bt + (size_t)(n0 + srow_) * K + scol;
  size_t rstride = (size_t)32 * K;
  int dofs = wave * 512;
  int akey = (fr & 7);

  auto stage = [&](int buf, int kb) {
#pragma unroll
    for (int i = 0; i < 4; ++i) {
      stage16(aSrc + i * rstride + kb, &As[buf][0] + i * 2048 + dofs);
      stage16(bSrc + i * rstride + kb, &Bs[buf][0] + i * 2048 + dofs);
    }
  };

  int NT = K >> 6;
  stage(0, 0);
  __syncthreads();
  for (int j = 0; j < NT; ++j) {
    int cur = j & 1;
    if (j + 1 < NT) stage(cur ^ 1, (j + 1) << 6);
    const char* Ab = (const char*)&As[cur][0];
    const char* Bb = (const char*)&Bs[cur][0];
#pragma unroll
    for (int ks = 0; ks < 2; ++ks) {
      bf16x8 af[4], bfv[4];
      int slot = (ks * 4 + fq) ^ akey;
#pragma unroll
      for (int i = 0; i < 4; ++i)
        af[i] = *(const bf16x8*)(Ab + (wm + i * 16 + fr) * 128 + slot * 16);
#pragma unroll
      for (int j2 = 0; j2 < 4; ++j2)
        bfv[j2] = *(const bf16x8*)(Bb + (wn + j2 * 16 + fr) * 128 + slot * 16);
      __builtin_amdgcn_s_setprio(1);
#pragma unroll
      for (int i = 0; i < 4; ++i)
#pragma unroll
        for (int j2 = 0; j2 < 4; ++j2)
          acc[i][j2] = mfma16(af[i], bfv[j2], acc[i][j2]);
      __builtin_amdgcn_s_setprio(0);
    }
    __syncthreads();
  }
#pragma unroll
  for (int i = 0; i < 4; ++i)
#pragma unroll
    for (int j = 0; j < 4; ++j)
#pragma unroll
      for (int r = 0; r < 4; ++r) {
        int row = m0 + wm + i * 16 + fq * 4 + r;
        int col = n0 + wn + j * 16 + fr;
        storeC(&C[(size_t)row * N + col], acc[i][j][r]);
      }
}

// ---------------- RMSNorm + RoPE (Q pre-scaled by SM_SCALE; fast trig) ----------------
__global__ __launch_bounds__(256) void normrope(u16* __restrict__ QKV,
                                                const float* __restrict__ qw,
                                                const float* __restrict__ kw) {
  int wq = threadIdx.x >> 6, lane = threadIdx.x & 63;
  int gid = blockIdx.x * 4 + wq;
  int token = gid / 40, head = gid % 40;
  int pos = token & (SEQ - 1);
  const float* wrow;
  int col;
  float sc;
  if (head < NH) { wrow = qw; col = head * HD; sc = SM_SCALE; }
  else           { wrow = kw; col = DMODEL + (head - NH) * HD; sc = 1.0f; }
  u16* row = QKV + (size_t)token * QKVN + col;
  ushort2 xv = *(const ushort2*)(row + 2 * lane);
  float x1 = bf2f(xv.x), x2 = bf2f(xv.y);
  float ssq = x1 * x1 + x2 * x2;
#pragma unroll
  for (int o = 32; o; o >>= 1) ssq += __shfl_xor(ssq, o, 64);
  float rms = rsqrtf(ssq * (1.0f / HD) + RMS_EPS);
  float y1 = x1 * rms * wrow[2 * lane] * sc;
  float y2 = x2 * rms * wrow[2 * lane + 1] * sc;
  float freq = exp2f((float)lane * -0.20762050593046014f);
  float ang = (float)pos * freq;
  float s, c;
  __sincosf(ang, &s, &c);
  ushort2 ov;
  ov.x = f2bf(y1 * c - y2 * s);
  ov.y = f2bf(y1 * s + y2 * c);
  *(ushort2*)(row + 2 * lane) = ov;
}

// ---------------- 8-wave 32x32 swapped-QK^T flash attention (r10, proven) ----------------
__global__ __launch_bounds__(512, 2) void attn(const u16* __restrict__ QKV, u16* __restrict__ O) {
  // XCD swizzle: grid 256 = 8 * 32
  int bid0 = blockIdx.x;
  int bid = (bid0 & 7) * 32 + (bid0 >> 3);
  int pairi = bid & 3, h = (bid >> 2) & 31, b = bid >> 7;
  int tid = threadIdx.x, wave = tid >> 6, lane = tid & 63;
  int qn = lane & 31, hi = lane >> 5;
  int hi4 = hi * 4, hi16 = hi * 16;
  int kvh = h >> 2;

  __shared__ __align__(16) u16 Ks[2][64 * 128];
  __shared__ __align__(16) u16 Vs[2][128 * 64];

  size_t tokb = (size_t)b * SEQ;
  const u16* Kg = QKV + tokb * QKVN + DMODEL + kvh * HD;
  const u16* Vg = Kg + NKV * HD;
  int srow = tid >> 4, sl = tid & 15;  // srow 0..31

  int kk0 = (qn & 7) << 4;
  int d0 = qn, d1 = 32 + qn, d2 = 64 + qn, d3 = 96 + qn;
  int vk0 = ((d0 ^ (d0 >> 3)) & 7) << 4;
  int vk1 = ((d1 ^ (d1 >> 3)) & 7) << 4;
  int vk2 = ((d2 ^ (d2 >> 3)) & 7) << 4;
  int vk3 = ((d3 ^ (d3 >> 3)) & 7) << 4;

  int4 vreg[2];
  auto loadV = [&](int kv0) {
#pragma unroll
    for (int i = 0; i < 2; ++i)
      vreg[i] = *(const int4*)(Vg + (size_t)(kv0 + i * 32 + srow) * QKVN + sl * 8);
  };
  auto stageK = [&](int buf, int kv0) {
#pragma unroll
    for (int i = 0; i < 2; ++i) {
      int row = i * 32 + srow;
      __builtin_amdgcn_global_load_lds(
          (const AS1 u32*)(Kg + (size_t)(kv0 + row) * QKVN + ((sl ^ (row & 7)) * 8)),
          (AS3 u32*)(&Ks[buf][0] + (i * 32 + wave * 4) * 128), 16, 0, 0);
    }
  };
  auto packV = [&](int buf) {
#pragma unroll
    for (int i = 0; i < 2; ++i) {
      int row = i * 32 + srow;
      int4 dvi = vreg[i];
      int4 dpi;
      dpi.x = __shfl_xor(dvi.x, 16, 64);
      dpi.y = __shfl_xor(dvi.y, 16, 64);
      dpi.z = __shfl_xor(dvi.z, 16, 64);
      dpi.w = __shfl_xor(dvi.w, 16, 64);
      if (((tid >> 4) & 1) == 0) {
        const u16* own = (const u16*)&dvi;
        const u16* par = (const u16*)&dpi;
#pragma unroll
        for (int j = 0; j < 8; ++j) {
          u32 wv = (u32)own[j] | ((u32)par[j] << 16);
          int d = sl * 8 + j;
          int vk = ((d ^ (d >> 3)) & 7) << 4;
          *(u32*)((char*)&Vs[buf][0] + d * 128 + ((2 * row) ^ vk)) = wv;
        }
      }
    }
  };

  for (int pass = 0; pass < 2; ++pass) {
    int chunk = pass ? (7 - pairi) : pairi;
    int chb = chunk * 256;
    int nt = (chunk + 1) * 4;
    int q0w = chb + wave * 32;
    int qabs = q0w + qn;
    int lim = chunk * 4 + (wave >> 1);
    int diag = q0w & ~63;

    bf16x8 qf[8];
    {
      const u16* qp = QKV + (tokb + q0w + qn) * QKVN + h * HD;
#pragma unroll
      for (int d = 0; d < 8; ++d) qf[d] = *(const bf16x8*)(qp + d * 16 + hi * 8);
    }

    f32x16 o0 = {}, o1 = {}, o2 = {}, o3 = {};
    float mrow = NEG_INF, lsum = 0.f;

    auto tile = [&](int kv0, const u16* Kl, const u16* Vl) {
      f32x16 p0v = {}, p1v = {};
      {
        const char* kb0 = (const char*)Kl + qn * 256;
        const char* kb1 = (const char*)Kl + (32 + qn) * 256;
        __builtin_amdgcn_s_setprio(1);
#pragma unroll
        for (int d = 0; d < 8; ++d) {
          bf16x8 k0 = *(const bf16x8*)(kb0 + ((d * 32 + hi16) ^ kk0));
          bf16x8 k1 = *(const bf16x8*)(kb1 + ((d * 32 + hi16) ^ kk0));
          p0v = mfma32(k0, qf[d], p0v);
          p1v = mfma32(k1, qf[d], p1v);
        }
        __builtin_amdgcn_s_setprio(0);
      }
      if (kv0 == diag) {
#pragma unroll
        for (int r = 0; r < 16; ++r) {
          int kva = kv0 + (r & 3) + 8 * (r >> 2) + hi4;
          if (kva > qabs) p0v[r] = NEG_INF;
          if (kva + 32 > qabs) p1v[r] = NEG_INF;
        }
      }
      float tmax = NEG_INF;
#pragma unroll
      for (int r = 0; r < 16; ++r) tmax = fmaxf(tmax, fmaxf(p0v[r], p1v[r]));
      tmax = fmaxf(tmax, __shfl_xor(tmax, 32, 64));
      if (!__all(tmax <= mrow + 8.0f)) {
        float nm = fmaxf(mrow, tmax);
        float corr = __expf(mrow - nm);
        mrow = nm;
        lsum *= corr;
#pragma unroll
        for (int r = 0; r < 16; ++r) {
          int srcl = (r & 3) + 8 * (r >> 2) + hi4;
          float cr = __shfl(corr, srcl, 64);
          o0[r] *= cr; o1[r] *= cr; o2[r] *= cr; o3[r] *= cr;
        }
      }
      float rs = 0.f;
#pragma unroll
      for (int r = 0; r < 16; ++r) {
        p0v[r] = __expf(p0v[r] - mrow);
        p1v[r] = __expf(p1v[r] - mrow);
        rs += p0v[r] + p1v[r];
      }
      rs += __shfl_xor(rs, 32, 64);
      lsum += rs;

      auto pv = [&](const f32x16& pk, int kvs) {
#pragma unroll
        for (int e = 0; e < 2; ++e) {
          u32 A = packbf(pk[e * 8 + 0], pk[e * 8 + 1]);
          u32 Bw = packbf(pk[e * 8 + 2], pk[e * 8 + 3]);
          u32 C = packbf(pk[e * 8 + 4], pk[e * 8 + 5]);
          u32 Dw = packbf(pk[e * 8 + 6], pk[e * 8 + 7]);
          u32 sA = __shfl_xor(A, 32, 64), sC = __shfl_xor(C, 32, 64);
          u32 sB = __shfl_xor(Bw, 32, 64), sD = __shfl_xor(Dw, 32, 64);
          union { u32 w[4]; bf16x8 v; } fr;
          fr.w[0] = hi ? sC : A;
          fr.w[1] = hi ? sD : Bw;
          fr.w[2] = hi ? C : sA;
          fr.w[3] = hi ? Dw : sB;
          int off = (kvs * 2 + e) * 32 + hi16;
          __builtin_amdgcn_s_setprio(1);
          o0 = mfma32(fr.v, *(const bf16x8*)((const char*)Vl + d0 * 128 + (off ^ vk0)), o0);
          o1 = mfma32(fr.v, *(const bf16x8*)((const char*)Vl + d1 * 128 + (off ^ vk1)), o1);
          o2 = mfma32(fr.v, *(const bf16x8*)((const char*)Vl + d2 * 128 + (off ^ vk2)), o2);
          o3 = mfma32(fr.v, *(const bf16x8*)((const char*)Vl + d3 * 128 + (off ^ vk3)), o3);
          __builtin_amdgcn_s_setprio(0);
        }
      };
      pv(p0v, 0);
      pv(p1v, 1);
    };

    loadV(0);
    stageK(0, 0);
    packV(0);
    __syncthreads();

    for (int t = 0; t < nt; ++t) {
      int cur = t & 1, nxt = cur ^ 1;
      bool more = (t + 1) < nt;
      if (more) {
        loadV((t + 1) * 64);
        stageK(nxt, (t + 1) * 64);
      }
      if (t <= lim) tile(t * 64, &Ks[cur][0], &Vs[cur][0]);
      if (more) packV(nxt);
      __syncthreads();
    }

#pragma unroll
    for (int r = 0; r < 16; ++r) {
      int ql = (r & 3) + 8 * (r >> 2) + hi4;
      float ls = __shfl(lsum, ql, 64);
      float inv = 1.0f / ls;
      size_t base = (tokb + chb + wave * 32 + ql) * (size_t)DMODEL + h * HD + qn;
      O[base] = f2bf(o0[r] * inv);
      O[base + 32] = f2bf(o1[r] * inv);
      O[base + 64] = f2bf(o2[r] * inv);
      O[base + 96] = f2bf(o3[r] * inv);
    }
  }
}

extern "C" void kernel_launch(void* const* d_in, const int* in_sizes, int n_in,
                              void* d_out, int out_size, void* d_ws, size_t ws_size,
                              hipStream_t stream) {
  const float* x  = (const float*)d_in[0];
  const float* Wq = (const float*)d_in[1];
  const float* Wk = (const float*)d_in[2];
  const float* Wv = (const float*)d_in[3];
  const float* Wo = (const float*)d_in[4];
  const float* qw = (const float*)d_in[5];
  const float* kw = (const float*)d_in[6];
  float* out = (float*)d_out;

  // Workspace (128 MiB):
  //   [0,   32M)  xb (bf16 x)  -- dead after GEMM1 -> reused as Wot
  //   [32M, 64M)  AO (attn out; region dead after GEMM1)
  //   [32M, 80M)  Wqkvt        -- dead after GEMM1
  //   [80M, 128M) QKVb
  char* ws = (char*)d_ws;
  u16* xb    = (u16*)(ws);
  u16* Wqkvt = (u16*)(ws + 33554432);
  u16* QKVb  = (u16*)(ws + 83886080);
  u16* Wot   = xb;
  u16* AO    = Wqkvt;

  cvt_f32_bf16<<<2048, 256, 0, stream>>>(x, xb, (2 * SEQ * DMODEL) / 4);
  tconv<<<dim3(DMODEL / 64, DMODEL / 64), 256, 0, stream>>>(Wq, Wqkvt, DMODEL, 0);
  tconv<<<dim3((NKV * HD) / 64, DMODEL / 64), 256, 0, stream>>>(Wk, Wqkvt, NKV * HD, DMODEL);
  tconv<<<dim3((NKV * HD) / 64, DMODEL / 64), 256, 0, stream>>>(Wv, Wqkvt, NKV * HD, DMODEL + NKV * HD);

  // gemm1: 1536 blocks -> single-buffer template
  gemm_sb<u16><<<(4096 / 128) * (QKVN / 128), 256, 0, stream>>>(xb, Wqkvt, QKVb, 4096, QKVN, DMODEL);
  normrope<<<(4096 * 40) / 4, 256, 0, stream>>>(QKVb, qw, kw);

  tconv<<<dim3(DMODEL / 64, DMODEL / 64), 256, 0, stream>>>(Wo, Wot, DMODEL, 0);
  attn<<<256, 512, 0, stream>>>(QKVb, AO);
  // gemm2: 1024 blocks -> double-buffer template (2 blocks/CU, exactly 2 generations)
  gemm_db<float><<<(4096 / 128) * (DMODEL / 128), 256, 0, stream>>>(AO, Wot, out, 4096, DMODEL, DMODEL);
}

// Round 15
// 549.296 us; speedup vs baseline: 1.2887x; 1.0285x over previous
//
#include <hip/hip_runtime.h>

typedef unsigned short u16;
typedef unsigned int u32;
typedef __attribute__((ext_vector_type(8))) short bf16x8;
typedef __attribute__((ext_vector_type(4))) float f32x4;
typedef __attribute__((ext_vector_type(16))) float f32x16;

#define NH 32
#define NKV 8
#define HD 128
#define SEQ 2048
#define DMODEL 4096
#define QKVN 6144
#define RMS_EPS 1e-6f
#define SM_SCALE 0.08838834764831845f
#define NEG_INF -1e30f

#define AS1 __attribute__((address_space(1)))
#define AS3 __attribute__((address_space(3)))

__device__ __forceinline__ u16 f2bf(float f) {
  unsigned int u = __float_as_uint(f);
  u += 0x7FFFu + ((u >> 16) & 1u);
  return (u16)(u >> 16);
}
__device__ __forceinline__ float bf2f(u16 b) {
  return __uint_as_float(((unsigned int)b) << 16);
}
__device__ __forceinline__ u32 packbf(float lo, float hi) {
  u32 a = __float_as_uint(lo) + 0x8000u;
  u32 b = __float_as_uint(hi) + 0x8000u;
  return __builtin_amdgcn_perm(b, a, 0x07060302u);
}

__device__ __forceinline__ f32x4 mfma16(bf16x8 a, bf16x8 b, f32x4 c) {
  return __builtin_amdgcn_mfma_f32_16x16x32_bf16(a, b, c, 0, 0, 0);
}
__device__ __forceinline__ f32x16 mfma32(bf16x8 a, bf16x8 b, f32x16 c) {
  return __builtin_amdgcn_mfma_f32_32x32x16_bf16(a, b, c, 0, 0, 0);
}

__device__ __forceinline__ void stage16(const u16* g, u16* l) {
  __builtin_amdgcn_global_load_lds((const AS1 u32*)g, (AS3 u32*)l, 16, 0, 0);
}

// ---------------- convert x: f32 -> bf16 ----------------
__global__ __launch_bounds__(256) void cvt_f32_bf16(const float* __restrict__ in,
                                                    u16* __restrict__ out, int n4) {
  int stride = gridDim.x * blockDim.x;
  for (int i = blockIdx.x * blockDim.x + threadIdx.x; i < n4; i += stride) {
    float4 v = ((const float4*)in)[i];
    ushort4 o;
    o.x = f2bf(v.x); o.y = f2bf(v.y); o.z = f2bf(v.z); o.w = f2bf(v.w);
    ((ushort4*)out)[i] = o;
  }
}

// ---------------- transpose-convert, 64x64 tile (r14 proven) ----------------
__device__ __forceinline__ void tconv_tile(const float* __restrict__ W, u16* __restrict__ Wt,
                                           int N, int rowoff, int n0, int k0, int tid) {
  __shared__ float t[64][66];
  int ln = tid & 63;
  int lk = tid >> 6;
#pragma unroll
  for (int i = 0; i < 16; ++i) {
    int kk = lk + i * 4;
    t[ln][kk] = W[(size_t)(k0 + kk) * N + n0 + ln];
  }
  __syncthreads();
  int kc = tid & 31;
  int nr = tid >> 5;
#pragma unroll
  for (int j = 0; j < 8; ++j) {
    int n = nr + j * 8;
    float2 f = *(const float2*)&t[n][kc * 2];
    ushort2 o;
    o.x = f2bf(f.x);
    o.y = f2bf(f.y);
    *(ushort2*)&Wt[(size_t)(rowoff + n0 + n) * DMODEL + k0 + kc * 2] = o;
  }
}

// single kernel for Wq/Wk/Wv (one launch): bx<64 -> Wq, 64..79 -> Wk, 80..95 -> Wv
__global__ __launch_bounds__(256) void tconv3(const float* __restrict__ Wq,
                                              const float* __restrict__ Wk,
                                              const float* __restrict__ Wv,
                                              u16* __restrict__ Wt) {
  int bx = blockIdx.x, k0 = blockIdx.y * 64, tid = threadIdx.x;
  if (bx < 64)       tconv_tile(Wq, Wt, DMODEL, 0, bx * 64, k0, tid);
  else if (bx < 80)  tconv_tile(Wk, Wt, NKV * HD, DMODEL, (bx - 64) * 64, k0, tid);
  else               tconv_tile(Wv, Wt, NKV * HD, DMODEL + NKV * HD, (bx - 80) * 64, k0, tid);
}

__global__ __launch_bounds__(256) void tconv(const float* __restrict__ W, u16* __restrict__ Wt,
                                             int N, int rowoff) {
  tconv_tile(W, Wt, N, rowoff, blockIdx.x * 64, blockIdx.y * 64, threadIdx.x);
}

__device__ __forceinline__ void storeC(u16* p, float v) { *p = f2bf(v); }
__device__ __forceinline__ void storeC(float* p, float v) { *p = v; }

// ---------------- GEMM db192: 128x192 tile, BK=64, explicit double-buffer ----------------
// For gemm1 (M=4096, N=6144): grid 32x32 = 1024 blocks = 2 EXACT generations at
// 2 blocks/CU (LDS 80KB). 4 waves (2M x 2N), per-wave 64x96 = 4x6 frags, 48 MFMA/iter.
// Same proven db pipeline: stage(j+1) -> compute(j) -> one __syncthreads.
template <typename OutT>
__global__ __launch_bounds__(256, 2) void gemm_db192(const u16* __restrict__ A,
                                                     const u16* __restrict__ Bt,
                                                     OutT* __restrict__ C, int M, int N, int K) {
  __shared__ __align__(16) u16 As[2][128 * 64];
  __shared__ __align__(16) u16 Bs[2][192 * 64];
  int nwg = gridDim.x, q8 = nwg >> 3, bid = blockIdx.x;
  int nid = (bid & 7) * q8 + (bid >> 3);
  int mt = M >> 7;
  int m0 = (nid % mt) * 128, n0 = (nid / mt) * 192;
  int tid = threadIdx.x, wave = tid >> 6, lane = tid & 63;
  int wm = (wave >> 1) * 64, wn = (wave & 1) * 96;
  f32x4 acc[4][6] = {};
  int fr = lane & 15, fq = lane >> 4;

  int srow_ = tid >> 3;
  int scol = ((tid & 7) ^ (srow_ & 7)) * 8;
  const u16* aSrc = A + (size_t)(m0 + srow_) * K + scol;
  const u16* bSrc = Bt + (size_t)(n0 + srow_) * K + scol;
  size_t rstride = (size_t)32 * K;
  int dofs = wave * 512;
  int akey = (fr & 7);

  auto stage = [&](int buf, int kb) {
#pragma unroll
    for (int i = 0; i < 4; ++i)
      stage16(aSrc + i * rstride + kb, &As[buf][0] + i * 2048 + dofs);
#pragma unroll
    for (int i = 0; i < 6; ++i)
      stage16(bSrc + i * rstride + kb, &Bs[buf][0] + i * 2048 + dofs);
  };

  int NT = K >> 6;
  stage(0, 0);
  __syncthreads();
  for (int j = 0; j < NT; ++j) {
    int cur = j & 1;
    if (j + 1 < NT) stage(cur ^ 1, (j + 1) << 6);
    const char* Ab = (const char*)&As[cur][0];
    const char* Bb = (const char*)&Bs[cur][0];
#pragma unroll
    for (int ks = 0; ks < 2; ++ks) {
      bf16x8 af[4], bfv[6];
      int slot = (ks * 4 + fq) ^ akey;
#pragma unroll
      for (int i = 0; i < 4; ++i)
        af[i] = *(const bf16x8*)(Ab + (wm + i * 16 + fr) * 128 + slot * 16);
#pragma unroll
      for (int j2 = 0; j2 < 6; ++j2)
        bfv[j2] = *(const bf16x8*)(Bb + (wn + j2 * 16 + fr) * 128 + slot * 16);
      __builtin_amdgcn_s_setprio(1);
#pragma unroll
      for (int i = 0; i < 4; ++i)
#pragma unroll
        for (int j2 = 0; j2 < 6; ++j2)
          acc[i][j2] = mfma16(af[i], bfv[j2], acc[i][j2]);
      __builtin_amdgcn_s_setprio(0);
    }
    __syncthreads();
  }
#pragma unroll
  for (int i = 0; i < 4; ++i)
#pragma unroll
    for (int j = 0; j < 6; ++j)
#pragma unroll
      for (int r = 0; r < 4; ++r) {
        int row = m0 + wm + i * 16 + fq * 4 + r;
        int col = n0 + wn + j * 16 + fr;
        storeC(&C[(size_t)row * N + col], acc[i][j][r]);
      }
}

// ---------------- GEMM db (r12 proven): 128x128, BK=64, double-buffer ----------------
template <typename OutT>
__global__ __launch_bounds__(256) void gemm_db(const u16* __restrict__ A, const u16* __restrict__ Bt,
                                               OutT* __restrict__ C, int M, int N, int K) {
  __shared__ __align__(16) u16 As[2][128 * 64];
  __shared__ __align__(16) u16 Bs[2][128 * 64];
  int nwg = gridDim.x, q8 = nwg >> 3, bid = blockIdx.x;
  int nid = (bid & 7) * q8 + (bid >> 3);
  int mt = M >> 7;
  int m0 = (nid % mt) * 128, n0 = (nid / mt) * 128;
  int tid = threadIdx.x, wave = tid >> 6, lane = tid & 63;
  int wm = (wave >> 1) * 64, wn = (wave & 1) * 64;
  f32x4 acc[4][4] = {};
  int fr = lane & 15, fq = lane >> 4;

  int srow_ = tid >> 3;
  int scol = ((tid & 7) ^ (srow_ & 7)) * 8;
  const u16* aSrc = A + (size_t)(m0 + srow_) * K + scol;
  const u16* bSrc = Bt + (size_t)(n0 + srow_) * K + scol;
  size_t rstride = (size_t)32 * K;
  int dofs = wave * 512;
  int akey = (fr & 7);

  auto stage = [&](int buf, int kb) {
#pragma unroll
    for (int i = 0; i < 4; ++i) {
      stage16(aSrc + i * rstride + kb, &As[buf][0] + i * 2048 + dofs);
      stage16(bSrc + i * rstride + kb, &Bs[buf][0] + i * 2048 + dofs);
    }
  };

  int NT = K >> 6;
  stage(0, 0);
  __syncthreads();
  for (int j = 0; j < NT; ++j) {
    int cur = j & 1;
    if (j + 1 < NT) stage(cur ^ 1, (j + 1) << 6);
    const char* Ab = (const char*)&As[cur][0];
    const char* Bb = (const char*)&Bs[cur][0];
#pragma unroll
    for (int ks = 0; ks < 2; ++ks) {
      bf16x8 af[4], bfv[4];
      int slot = (ks * 4 + fq) ^ akey;
#pragma unroll
      for (int i = 0; i < 4; ++i)
        af[i] = *(const bf16x8*)(Ab + (wm + i * 16 + fr) * 128 + slot * 16);
#pragma unroll
      for (int j2 = 0; j2 < 4; ++j2)
        bfv[j2] = *(const bf16x8*)(Bb + (wn + j2 * 16 + fr) * 128 + slot * 16);
      __builtin_amdgcn_s_setprio(1);
#pragma unroll
      for (int i = 0; i < 4; ++i)
#pragma unroll
        for (int j2 = 0; j2 < 4; ++j2)
          acc[i][j2] = mfma16(af[i], bfv[j2], acc[i][j2]);
      __builtin_amdgcn_s_setprio(0);
    }
    __syncthreads();
  }
#pragma unroll
  for (int i = 0; i < 4; ++i)
#pragma unroll
    for (int j = 0; j < 4; ++j)
#pragma unroll
      for (int r = 0; r < 4; ++r) {
        int row = m0 + wm + i * 16 + fq * 4 + r;
        int col = n0 + wn + j * 16 + fr;
        storeC(&C[(size_t)row * N + col], acc[i][j][r]);
      }
}

// ---------------- RMSNorm + RoPE (Q pre-scaled by SM_SCALE; fast trig) ----------------
__global__ __launch_bounds__(256) void normrope(u16* __restrict__ QKV,
                                                const float* __restrict__ qw,
                                                const float* __restrict__ kw) {
  int wq = threadIdx.x >> 6, lane = threadIdx.x & 63;
  int gid = blockIdx.x * 4 + wq;
  int token = gid / 40, head = gid % 40;
  int pos = token & (SEQ - 1);
  const float* wrow;
  int col;
  float sc;
  if (head < NH) { wrow = qw; col = head * HD; sc = SM_SCALE; }
  else           { wrow = kw; col = DMODEL + (head - NH) * HD; sc = 1.0f; }
  u16* row = QKV + (size_t)token * QKVN + col;
  ushort2 xv = *(const ushort2*)(row + 2 * lane);
  float x1 = bf2f(xv.x), x2 = bf2f(xv.y);
  float ssq = x1 * x1 + x2 * x2;
#pragma unroll
  for (int o = 32; o; o >>= 1) ssq += __shfl_xor(ssq, o, 64);
  float rms = rsqrtf(ssq * (1.0f / HD) + RMS_EPS);
  float y1 = x1 * rms * wrow[2 * lane] * sc;
  float y2 = x2 * rms * wrow[2 * lane + 1] * sc;
  float freq = exp2f((float)lane * -0.20762050593046014f);
  float ang = (float)pos * freq;
  float s, c;
  __sincosf(ang, &s, &c);
  ushort2 ov;
  ov.x = f2bf(y1 * c - y2 * s);
  ov.y = f2bf(y1 * s + y2 * c);
  *(ushort2*)(row + 2 * lane) = ov;
}

// ---------------- 8-wave 32x32 swapped-QK^T flash attention (r10, proven) ----------------
__global__ __launch_bounds__(512, 2) void attn(const u16* __restrict__ QKV, u16* __restrict__ O) {
  int bid0 = blockIdx.x;
  int bid = (bid0 & 7) * 32 + (bid0 >> 3);
  int pairi = bid & 3, h = (bid >> 2) & 31, b = bid >> 7;
  int tid = threadIdx.x, wave = tid >> 6, lane = tid & 63;
  int qn = lane & 31, hi = lane >> 5;
  int hi4 = hi * 4, hi16 = hi * 16;
  int kvh = h >> 2;

  __shared__ __align__(16) u16 Ks[2][64 * 128];
  __shared__ __align__(16) u16 Vs[2][128 * 64];

  size_t tokb = (size_t)b * SEQ;
  const u16* Kg = QKV + tokb * QKVN + DMODEL + kvh * HD;
  const u16* Vg = Kg + NKV * HD;
  int srow = tid >> 4, sl = tid & 15;

  int kk0 = (qn & 7) << 4;
  int d0 = qn, d1 = 32 + qn, d2 = 64 + qn, d3 = 96 + qn;
  int vk0 = ((d0 ^ (d0 >> 3)) & 7) << 4;
  int vk1 = ((d1 ^ (d1 >> 3)) & 7) << 4;
  int vk2 = ((d2 ^ (d2 >> 3)) & 7) << 4;
  int vk3 = ((d3 ^ (d3 >> 3)) & 7) << 4;

  int4 vreg[2];
  auto loadV = [&](int kv0) {
#pragma unroll
    for (int i = 0; i < 2; ++i)
      vreg[i] = *(const int4*)(Vg + (size_t)(kv0 + i * 32 + srow) * QKVN + sl * 8);
  };
  auto stageK = [&](int buf, int kv0) {
#pragma unroll
    for (int i = 0; i < 2; ++i) {
      int row = i * 32 + srow;
      __builtin_amdgcn_global_load_lds(
          (const AS1 u32*)(Kg + (size_t)(kv0 + row) * QKVN + ((sl ^ (row & 7)) * 8)),
          (AS3 u32*)(&Ks[buf][0] + (i * 32 + wave * 4) * 128), 16, 0, 0);
    }
  };
  auto packV = [&](int buf) {
#pragma unroll
    for (int i = 0; i < 2; ++i) {
      int row = i * 32 + srow;
      int4 dvi = vreg[i];
      int4 dpi;
      dpi.x = __shfl_xor(dvi.x, 16, 64);
      dpi.y = __shfl_xor(dvi.y, 16, 64);
      dpi.z = __shfl_xor(dvi.z, 16, 64);
      dpi.w = __shfl_xor(dvi.w, 16, 64);
      if (((tid >> 4) & 1) == 0) {
        const u16* own = (const u16*)&dvi;
        const u16* par = (const u16*)&dpi;
#pragma unroll
        for (int j = 0; j < 8; ++j) {
          u32 wv = (u32)own[j] | ((u32)par[j] << 16);
          int d = sl * 8 + j;
          int vk = ((d ^ (d >> 3)) & 7) << 4;
          *(u32*)((char*)&Vs[buf][0] + d * 128 + ((2 * row) ^ vk)) = wv;
        }
      }
    }
  };

  for (int pass = 0; pass < 2; ++pass) {
    int chunk = pass ? (7 - pairi) : pairi;
    int chb = chunk * 256;
    int nt = (chunk + 1) * 4;
    int q0w = chb + wave * 32;
    int qabs = q0w + qn;
    int lim = chunk * 4 + (wave >> 1);
    int diag = q0w & ~63;

    bf16x8 qf[8];
    {
      const u16* qp = QKV + (tokb + q0w + qn) * QKVN + h * HD;
#pragma unroll
      for (int d = 0; d < 8; ++d) qf[d] = *(const bf16x8*)(qp + d * 16 + hi * 8);
    }

    f32x16 o0 = {}, o1 = {}, o2 = {}, o3 = {};
    float mrow = NEG_INF, lsum = 0.f;

    auto tile = [&](int kv0, const u16* Kl, const u16* Vl) {
      f32x16 p0v = {}, p1v = {};
      {
        const char* kb0 = (const char*)Kl + qn * 256;
        const char* kb1 = (const char*)Kl + (32 + qn) * 256;
        __builtin_amdgcn_s_setprio(1);
#pragma unroll
        for (int d = 0; d < 8; ++d) {
          bf16x8 k0 = *(const bf16x8*)(kb0 + ((d * 32 + hi16) ^ kk0));
          bf16x8 k1 = *(const bf16x8*)(kb1 + ((d * 32 + hi16) ^ kk0));
          p0v = mfma32(k0, qf[d], p0v);
          p1v = mfma32(k1, qf[d], p1v);
        }
        __builtin_amdgcn_s_setprio(0);
      }
      if (kv0 == diag) {
#pragma unroll
        for (int r = 0; r < 16; ++r) {
          int kva = kv0 + (r & 3) + 8 * (r >> 2) + hi4;
          if (kva > qabs) p0v[r] = NEG_INF;
          if (kva + 32 > qabs) p1v[r] = NEG_INF;
        }
      }
      float tmax = NEG_INF;
#pragma unroll
      for (int r = 0; r < 16; ++r) tmax = fmaxf(tmax, fmaxf(p0v[r], p1v[r]));
      tmax = fmaxf(tmax, __shfl_xor(tmax, 32, 64));
      if (!__all(tmax <= mrow + 8.0f)) {
        float nm = fmaxf(mrow, tmax);
        float corr = __expf(mrow - nm);
        mrow = nm;
        lsum *= corr;
#pragma unroll
        for (int r = 0; r < 16; ++r) {
          int srcl = (r & 3) + 8 * (r >> 2) + hi4;
          float cr = __shfl(corr, srcl, 64);
          o0[r] *= cr; o1[r] *= cr; o2[r] *= cr; o3[r] *= cr;
        }
      }
      float rs = 0.f;
#pragma unroll
      for (int r = 0; r < 16; ++r) {
        p0v[r] = __expf(p0v[r] - mrow);
        p1v[r] = __expf(p1v[r] - mrow);
        rs += p0v[r] + p1v[r];
      }
      rs += __shfl_xor(rs, 32, 64);
      lsum += rs;

      auto pv = [&](const f32x16& pk, int kvs) {
#pragma unroll
        for (int e = 0; e < 2; ++e) {
          u32 A = packbf(pk[e * 8 + 0], pk[e * 8 + 1]);
          u32 Bw = packbf(pk[e * 8 + 2], pk[e * 8 + 3]);
          u32 C = packbf(pk[e * 8 + 4], pk[e * 8 + 5]);
          u32 Dw = packbf(pk[e * 8 + 6], pk[e * 8 + 7]);
          u32 sA = __shfl_xor(A, 32, 64), sC = __shfl_xor(C, 32, 64);
          u32 sB = __shfl_xor(Bw, 32, 64), sD = __shfl_xor(Dw, 32, 64);
          union { u32 w[4]; bf16x8 v; } fr;
          fr.w[0] = hi ? sC : A;
          fr.w[1] = hi ? sD : Bw;
          fr.w[2] = hi ? C : sA;
          fr.w[3] = hi ? Dw : sB;
          int off = (kvs * 2 + e) * 32 + hi16;
          __builtin_amdgcn_s_setprio(1);
          o0 = mfma32(fr.v, *(const bf16x8*)((const char*)Vl + d0 * 128 + (off ^ vk0)), o0);
          o1 = mfma32(fr.v, *(const bf16x8*)((const char*)Vl + d1 * 128 + (off ^ vk1)), o1);
          o2 = mfma32(fr.v, *(const bf16x8*)((const char*)Vl + d2 * 128 + (off ^ vk2)), o2);
          o3 = mfma32(fr.v, *(const bf16x8*)((const char*)Vl + d3 * 128 + (off ^ vk3)), o3);
          __builtin_amdgcn_s_setprio(0);
        }
      };
      pv(p0v, 0);
      pv(p1v, 1);
    };

    loadV(0);
    stageK(0, 0);
    packV(0);
    __syncthreads();

    for (int t = 0; t < nt; ++t) {
      int cur = t & 1, nxt = cur ^ 1;
      bool more = (t + 1) < nt;
      if (more) {
        loadV((t + 1) * 64);
        stageK(nxt, (t + 1) * 64);
      }
      if (t <= lim) tile(t * 64, &Ks[cur][0], &Vs[cur][0]);
      if (more) packV(nxt);
      __syncthreads();
    }

#pragma unroll
    for (int r = 0; r < 16; ++r) {
      int ql = (r & 3) + 8 * (r >> 2) + hi4;
      float ls = __shfl(lsum, ql, 64);
      float inv = 1.0f / ls;
      size_t base = (tokb + chb + wave * 32 + ql) * (size_t)DMODEL + h * HD + qn;
      O[base] = f2bf(o0[r] * inv);
      O[base + 32] = f2bf(o1[r] * inv);
      O[base + 64] = f2bf(o2[r] * inv);
      O[base + 96] = f2bf(o3[r] * inv);
    }
  }
}

extern "C" void kernel_launch(void* const* d_in, const int* in_sizes, int n_in,
                              void* d_out, int out_size, void* d_ws, size_t ws_size,
                              hipStream_t stream) {
  const float* x  = (const float*)d_in[0];
  const float* Wq = (const float*)d_in[1];
  const float* Wk = (const float*)d_in[2];
  const float* Wv = (const float*)d_in[3];
  const float* Wo = (const float*)d_in[4];
  const float* qw = (const float*)d_in[5];
  const float* kw = (const float*)d_in[6];
  float* out = (float*)d_out;

  // Workspace (128 MiB):
  //   [0,   32M)  xb (bf16 x)  -- dead after GEMM1 -> reused as Wot
  //   [32M, 64M)  AO (attn out; region dead after GEMM1)
  //   [32M, 80M)  Wqkvt        -- dead after GEMM1
  //   [80M, 128M) QKVb
  char* ws = (char*)d_ws;
  u16* xb    = (u16*)(ws);
  u16* Wqkvt = (u16*)(ws + 33554432);
  u16* QKVb  = (u16*)(ws + 83886080);
  u16* Wot   = xb;
  u16* AO    = Wqkvt;

  cvt_f32_bf16<<<2048, 256, 0, stream>>>(x, xb, (2 * SEQ * DMODEL) / 4);
  tconv3<<<dim3(96, DMODEL / 64), 256, 0, stream>>>(Wq, Wk, Wv, Wqkvt);

  // gemm1: 128x192 tile -> 1024 blocks = 2 exact generations at 2 blocks/CU
  gemm_db192<u16><<<(4096 / 128) * (QKVN / 192), 256, 0, stream>>>(xb, Wqkvt, QKVb, 4096, QKVN, DMODEL);
  normrope<<<(4096 * 40) / 4, 256, 0, stream>>>(QKVb, qw, kw);

  tconv<<<dim3(DMODEL / 64, DMODEL / 64), 256, 0, stream>>>(Wo, Wot, DMODEL, 0);
  attn<<<256, 512, 0, stream>>>(QKVb, AO);
  // gemm2: 1024 blocks -> double-buffer template (2 blocks/CU, exactly 2 generations)
  gemm_db<float><<<(4096 / 128) * (DMODEL / 128), 256, 0, stream>>>(AO, Wot, out, 4096, DMODEL, DMODEL);
}